// Round 8
// baseline (1425.187 us; speedup 1.0000x reference)
//
#include <hip/hip_runtime.h>
#include <hip/hip_bf16.h>
#include <stdint.h>

typedef short bf16x8 __attribute__((ext_vector_type(8)));
typedef float floatx4 __attribute__((ext_vector_type(4)));

#define N_ROWS 65536
#define V_DIM 2048
#define E_DIM 1024

__device__ __forceinline__ short f2bf(float x) {
  union { float f; uint32_t u; } c; c.f = x;
  uint32_t r = (c.u + 0x7FFFu + ((c.u >> 16) & 1u)) >> 16;
  return (short)(uint16_t)r;
}
__device__ __forceinline__ float bf16f(short b) {
  union { uint32_t u; float f; } c; c.u = ((uint32_t)(uint16_t)b) << 16;
  return c.f;
}

__device__ __forceinline__ float wave_sum(float v) {
#pragma unroll
  for (int o = 32; o > 0; o >>= 1) v += __shfl_xor(v, o);
  return v;
}
__device__ __forceinline__ float wave_max(float v) {
#pragma unroll
  for (int o = 32; o > 0; o >>= 1) v = fmaxf(v, __shfl_xor(v, o));
  return v;
}

__device__ __forceinline__ void gll16(const short* g, short* l) {
  __builtin_amdgcn_global_load_lds(
      (const __attribute__((address_space(1))) void*)g,
      (__attribute__((address_space(3))) void*)l, 16, 0, 0);
}

// fallback 128B-row swizzled fragment read
#define FRAG(base, R, c) \
  (*(const bf16x8*)((const char*)(base) + ((R) << 7) + (((((c) >> 3) ^ ((R) & 7))) << 4)))

// ---------------- normalize emb rows -> bf16 embn [V][E] and embnT [E][V] ----
__global__ __launch_bounds__(256) void k_norm_emb(const float* __restrict__ W,
                                                  short* __restrict__ embn,
                                                  short* __restrict__ embnT) {
  const int v = blockIdx.x;
  const int t = threadIdx.x;
  const int w = t >> 6, l = t & 63;
  const float4 val = *(const float4*)&W[(size_t)v * E_DIM + t * 4];
  float ss = val.x * val.x + val.y * val.y + val.z * val.z + val.w * val.w;
  ss = wave_sum(ss);
  __shared__ float red[4];
  if (l == 0) red[w] = ss;
  __syncthreads();
  ss = red[0] + red[1] + red[2] + red[3];
  const float inv = 1.0f / fmaxf(sqrtf(ss), 1e-12f);
  short4 o;
  o.x = f2bf(val.x * inv);
  o.y = f2bf(val.y * inv);
  o.z = f2bf(val.z * inv);
  o.w = f2bf(val.w * inv);
  *(short4*)&embn[(size_t)v * E_DIM + t * 4] = o;
  embnT[(size_t)(t * 4 + 0) * V_DIM + v] = o.x;
  embnT[(size_t)(t * 4 + 1) * V_DIM + v] = o.y;
  embnT[(size_t)(t * 4 + 2) * V_DIM + v] = o.z;
  embnT[(size_t)(t * 4 + 3) * V_DIM + v] = o.w;
}

// ---------------- normalize z rows, fold in kappa_q/T, -> bf16 zn [N][E] -----
__global__ __launch_bounds__(256) void k_norm_z(const float* __restrict__ Z,
                                                short* __restrict__ zn) {
  const int w = threadIdx.x >> 6, l = threadIdx.x & 63;
  const int row = blockIdx.x * 4 + w;
  const float* zr = Z + (size_t)row * E_DIM;
  float4 v[4];
  float ss = 0.f;
#pragma unroll
  for (int i = 0; i < 4; ++i) {
    v[i] = *(const float4*)&zr[(i * 64 + l) * 4];
    ss += v[i].x * v[i].x + v[i].y * v[i].y + v[i].z * v[i].z + v[i].w * v[i].w;
  }
  ss = wave_sum(ss);
  const float SCALE = 2.0f * (expf(-2.995732273553991f) + 1.0f);  // kappa_q / T
  const float inv = SCALE / fmaxf(sqrtf(ss), 1e-12f);
  short* zo = zn + (size_t)row * E_DIM;
#pragma unroll
  for (int i = 0; i < 4; ++i) {
    short4 o;
    o.x = f2bf(v[i].x * inv);
    o.y = f2bf(v[i].y * inv);
    o.z = f2bf(v[i].z * inv);
    o.w = f2bf(v[i].w * inv);
    *(short4*)&zo[(i * 64 + l) * 4] = o;
  }
}

// =============== FAST PATH: 256x256 tile, BK=32, 4-buffer ring (R6 mainloop:
// one barrier + vmcnt(4) per K-tile, register look-ahead).
// EPI 0: U register-prefetch during last tiles; gumbel-exp -> Pb + partials.
// EPI 1: invsum-scaled -> C; fused tokens write from staged A (replaces
//        k_token_norm): each thread reads back its own staged 2x16B and stores
//        f32 tokens for tiles kt>>4 == bx.
template <int KDIM, int NBX, int EPI>
__global__ __launch_bounds__(512, 2) void k_gemm8(
    const short* __restrict__ A, const short* __restrict__ B,
    const float* __restrict__ U, short* __restrict__ Pb,
    float* __restrict__ partials, const float* __restrict__ invsum,
    float* __restrict__ C, float* __restrict__ tokens, int cpx) {
  __shared__ __align__(16) short Sm[65536];  // A ring: 4 x 16KB; B ring at byte 65536
  const int NT = KDIM / 32;
  const int tid = threadIdx.x;
  const int wv = tid >> 6, lane = tid & 63;
  const int lr = lane & 15, lh = lane >> 4;
  const int wr = wv >> 2, wc = wv & 3;  // 2x4 wave grid
  // XCD-chunked bijective swizzle (grid multiple of 8)
  const int d = blockIdx.x;
  const int L = (d & 7) * cpx + (d >> 3);
  const int by = L / NBX, bx = L % NBX;
  const int m0 = by * 256, n0 = bx * 256;
  // staging: linear LDS dest; pre-swizzled global source granule
  const int sg = (((lane & 3) ^ ((lane >> 2) & 3) ^ ((lane >> 4) & 3)) << 3);
  const int srow = wv * 16 + (lane >> 2);
  const short* gA = A + (size_t)(m0 + srow) * KDIM + sg;
  const short* gB = B + (size_t)(n0 + srow) * KDIM + sg;
  // fragment read: slot = lh ^ f(R), f(R) = (lr ^ (lr>>2)) & 3 for all frag rows
  const int fslot = lh ^ ((lr ^ (lr >> 2)) & 3);
  const int aoff = wr * 8192 + lr * 64 + fslot * 16;  // bytes within A buffer
  const int boff = wc * 4096 + lr * 64 + fslot * 16;  // bytes within B buffer

  const int gr0 = m0 + wr * 128 + lh * 4;
  const int gc0 = n0 + wc * 64 + lr;
  const float* Ug = U + (size_t)gr0 * V_DIM + gc0;  // EPI0 only

  // EPI1: invsum for this thread's staged rows (tokens scale)
  float inv0 = 0.f, inv1 = 0.f;
  if (EPI == 1) {
    inv0 = invsum[m0 + srow];
    inv1 = invsum[m0 + 128 + srow];
  }

  bf16x8 af[4], afN[4], bfr[4];
  floatx4 acc[8][4] = {};
  float u01[32], u23[32];

// U prefetch: rows m=2P..2P+1 of this thread's epilogue tile, 32 scalar loads
#define UPREF(arr, P)                                                               \
  {                                                                                 \
    _Pragma("unroll")                                                               \
    for (int mm = 0; mm < 2; ++mm)                                                  \
      _Pragma("unroll")                                                             \
      for (int n = 0; n < 4; ++n)                                                   \
        _Pragma("unroll")                                                           \
        for (int j = 0; j < 4; ++j)                                                 \
          arr[mm * 16 + n * 4 + j] =                                                \
              Ug[(size_t)(((2 * (P) + mm) * 16 + j)) * V_DIM + n * 16];             \
  }

#define STAGE(KT)                                                                   \
  {                                                                                 \
    short* An_ = Sm + ((KT) & 3) * 8192;                                            \
    short* Bn_ = Sm + 32768 + ((KT) & 3) * 8192;                                    \
    const size_t kc_ = (size_t)(KT) * 32;                                           \
    gll16(gA + kc_, An_ + wv * 512);                                                \
    gll16(gA + (size_t)128 * KDIM + kc_, An_ + 4096 + wv * 512);                    \
    gll16(gB + kc_, Bn_ + wv * 512);                                                \
    gll16(gB + (size_t)128 * KDIM + kc_, Bn_ + 4096 + wv * 512);                    \
  }
#define RD_B(KT)                                                                    \
  {                                                                                 \
    const char* Bb_ = (const char*)Sm + 65536 + ((KT) & 3) * 16384;                 \
    _Pragma("unroll")                                                               \
    for (int n = 0; n < 4; ++n) bfr[n] = *(const bf16x8*)(Bb_ + boff + n * 1024);   \
  }
#define RD_ALO(KT)                                                                  \
  {                                                                                 \
    const char* Ab_ = (const char*)Sm + ((KT) & 3) * 16384;                         \
    _Pragma("unroll")                                                               \
    for (int i = 0; i < 4; ++i) af[i] = *(const bf16x8*)(Ab_ + aoff + i * 1024);    \
  }
#define RD_AHI(KT)                                                                  \
  {                                                                                 \
    const char* Ab_ = (const char*)Sm + ((KT) & 3) * 16384;                         \
    _Pragma("unroll")                                                               \
    for (int i = 0; i < 4; ++i)                                                     \
      afN[i] = *(const bf16x8*)(Ab_ + aoff + 4096 + i * 1024);                      \
  }
#define MF_LO                                                                       \
  __builtin_amdgcn_s_setprio(1);                                                    \
  _Pragma("unroll")                                                                 \
  for (int i = 0; i < 4; ++i) {                                                     \
    _Pragma("unroll")                                                               \
    for (int n = 0; n < 4; ++n)                                                     \
      acc[i][n] = __builtin_amdgcn_mfma_f32_16x16x32_bf16(af[i], bfr[n], acc[i][n], 0, 0, 0); \
  }                                                                                 \
  __builtin_amdgcn_s_setprio(0);
#define MF_HI                                                                       \
  __builtin_amdgcn_s_setprio(1);                                                    \
  _Pragma("unroll")                                                                 \
  for (int i = 0; i < 4; ++i) {                                                     \
    _Pragma("unroll")                                                               \
    for (int n = 0; n < 4; ++n)                                                     \
      acc[4 + i][n] = __builtin_amdgcn_mfma_f32_16x16x32_bf16(afN[i], bfr[n], acc[4 + i][n], 0, 0, 0); \
  }                                                                                 \
  __builtin_amdgcn_s_setprio(0);
// EPI1 fused tokens write: read back own staged A (== Pb bits), scale, store f32
#define TOKW(KT)                                                                    \
  if (EPI == 1 && ((KT) >> 4) == bx) {                                              \
    const short* myA_ = Sm + ((KT) & 3) * 8192 + wv * 512 + lane * 8;               \
    const bf16x8 v0_ = *(const bf16x8*)myA_;                                        \
    const bf16x8 v1_ = *(const bf16x8*)(myA_ + 4096);                               \
    const size_t c0_ = (size_t)(KT) * 32 + sg;                                      \
    float4 a_, b_;                                                                  \
    a_.x = bf16f(v0_[0]) * inv0; a_.y = bf16f(v0_[1]) * inv0;                       \
    a_.z = bf16f(v0_[2]) * inv0; a_.w = bf16f(v0_[3]) * inv0;                       \
    b_.x = bf16f(v0_[4]) * inv0; b_.y = bf16f(v0_[5]) * inv0;                       \
    b_.z = bf16f(v0_[6]) * inv0; b_.w = bf16f(v0_[7]) * inv0;                       \
    *(float4*)&tokens[(size_t)(m0 + srow) * KDIM + c0_] = a_;                       \
    *(float4*)&tokens[(size_t)(m0 + srow) * KDIM + c0_ + 4] = b_;                   \
    a_.x = bf16f(v1_[0]) * inv1; a_.y = bf16f(v1_[1]) * inv1;                       \
    a_.z = bf16f(v1_[2]) * inv1; a_.w = bf16f(v1_[3]) * inv1;                       \
    b_.x = bf16f(v1_[4]) * inv1; b_.y = bf16f(v1_[5]) * inv1;                       \
    b_.z = bf16f(v1_[6]) * inv1; b_.w = bf16f(v1_[7]) * inv1;                       \
    *(float4*)&tokens[(size_t)(m0 + 128 + srow) * KDIM + c0_] = a_;                 \
    *(float4*)&tokens[(size_t)(m0 + 128 + srow) * KDIM + c0_ + 4] = b_;             \
  }

  // prologue
  STAGE(0);
  STAGE(1);
  asm volatile("s_waitcnt vmcnt(4)" ::: "memory");
  __builtin_amdgcn_s_barrier();
  __builtin_amdgcn_sched_barrier(0);
  RD_B(0);
  RD_ALO(0);

#pragma unroll 2
  for (int kt = 0; kt < NT - 2; ++kt) {
    if (EPI == 0 && kt == NT - 6) UPREF(u01, 0);   // U streams under compute
    if (EPI == 0 && kt == NT - 4) UPREF(u23, 1);
    STAGE(kt + 2);          // DMA kt+2 (slot (kt+2)&3)
    RD_AHI(kt);             // A.hi of current tile, drains under MF_LO
    MF_LO;
    MF_HI;
    TOKW(kt);
    asm volatile("s_waitcnt vmcnt(4)" ::: "memory");  // kt+1's DMA done
    __builtin_amdgcn_s_barrier();
    __builtin_amdgcn_sched_barrier(0);
    RD_B(kt + 1);           // look-ahead reads: used next iteration
    RD_ALO(kt + 1);
  }
  // tile NT-2
  RD_AHI(NT - 2);
  MF_LO;
  MF_HI;
  TOKW(NT - 2);
  asm volatile("s_waitcnt vmcnt(0)" ::: "memory");
  __builtin_amdgcn_s_barrier();
  __builtin_amdgcn_sched_barrier(0);
  RD_B(NT - 1);
  RD_ALO(NT - 1);
  // tile NT-1
  RD_AHI(NT - 1);
  MF_LO;
  MF_HI;
  TOKW(NT - 1);
#undef STAGE
#undef RD_B
#undef RD_ALO
#undef RD_AHI
#undef MF_LO
#undef MF_HI
#undef TOKW

  if (EPI == 0) {
    float rs[8][4] = {};
    float u45[32], u67[32];
    UPREF(u45, 2);  // issue before compute: latency hides under m0..1 exp pass
#define EPI_PAIR(P, arr)                                                            \
    _Pragma("unroll")                                                               \
    for (int mm = 0; mm < 2; ++mm) {                                                \
      const int m = 2 * (P) + mm;                                                   \
      _Pragma("unroll")                                                             \
      for (int n = 0; n < 4; ++n) {                                                 \
        const int col = gc0 + n * 16;                                               \
        _Pragma("unroll")                                                           \
        for (int j = 0; j < 4; ++j) {                                               \
          const int row = gr0 + m * 16 + j;                                         \
          const size_t idx = (size_t)row * V_DIM + col;                             \
          const float u = arr[mm * 16 + n * 4 + j];                                 \
          const float e = __expf(acc[m][n][j] -                                     \
                                 2.f * __logf(-__logf(u + 1e-10f) + 1e-10f));       \
          const short eb = f2bf(e);                                                 \
          Pb[idx] = eb;                                                             \
          rs[m][j] += bf16f(eb);                                                    \
        }                                                                           \
      }                                                                             \
    }
    EPI_PAIR(0, u01);
    UPREF(u67, 3);
    EPI_PAIR(1, u23);
    EPI_PAIR(2, u45);
    EPI_PAIR(3, u67);
#undef EPI_PAIR
#pragma unroll
    for (int m = 0; m < 8; ++m)
#pragma unroll
      for (int j = 0; j < 4; ++j) {
        float s = rs[m][j];
        s += __shfl_xor(s, 1); s += __shfl_xor(s, 2);
        s += __shfl_xor(s, 4); s += __shfl_xor(s, 8);
        if (lr == 0)
          partials[(size_t)(gr0 + m * 16 + j) * 32 + bx * 4 + wc] = s;
      }
  } else {
#pragma unroll
    for (int m = 0; m < 8; ++m)
#pragma unroll
      for (int j = 0; j < 4; ++j) {
        const int row = gr0 + m * 16 + j;
        const float s = invsum[row];
#pragma unroll
        for (int n = 0; n < 4; ++n)
          C[(size_t)row * E_DIM + gc0 + n * 16] = acc[m][n][j] * s;
      }
  }
#undef UPREF
}

// invsum[r] = 1 / sum(partials[r][0..32))
__global__ __launch_bounds__(256) void k_rowsum_inv(const float* __restrict__ partials,
                                                    float* __restrict__ invsum) {
  const int r = blockIdx.x * 256 + threadIdx.x;
  const float4* p = (const float4*)&partials[(size_t)r * 32];
  float s = 0.f;
#pragma unroll
  for (int i = 0; i < 8; ++i) { float4 v = p[i]; s += v.x + v.y + v.z + v.w; }
  invsum[r] = 1.f / s;
}

// =============== FALLBACK PATH (round-1, known-correct) ======================
__global__ __launch_bounds__(256) void k_gemm_nt(const short* __restrict__ A,
                                                 const short* __restrict__ B,
                                                 float* __restrict__ C,
                                                 int lda, int ldb, int ldc, int K) {
  __shared__ __align__(16) short As[128][64];
  __shared__ __align__(16) short Bs[128][64];
  const int t = threadIdx.x;
  const int w = t >> 6, l = t & 63;
  const int lr = l & 15, lh = l >> 4;
  const int m0 = blockIdx.y * 128, n0 = blockIdx.x * 128;
  const int wm = (w >> 1) * 64, wn = (w & 1) * 64;
  floatx4 acc[4][4] = {};
  for (int k0 = 0; k0 < K; k0 += 64) {
    __syncthreads();
#pragma unroll
    for (int i = 0; i < 4; ++i) {
      const int c = i * 256 + t;
      const int r = c >> 3, c8 = (c & 7) * 8;
      *(bf16x8*)&As[r][c8] = *(const bf16x8*)&A[(size_t)(m0 + r) * lda + k0 + c8];
      *(bf16x8*)&Bs[r][c8] = *(const bf16x8*)&B[(size_t)(n0 + r) * ldb + k0 + c8];
    }
    __syncthreads();
#pragma unroll
    for (int kk = 0; kk < 64; kk += 32) {
      bf16x8 af[4], bfr[4];
#pragma unroll
      for (int m = 0; m < 4; ++m) af[m] = *(const bf16x8*)&As[wm + m * 16 + lr][kk + lh * 8];
#pragma unroll
      for (int n = 0; n < 4; ++n) bfr[n] = *(const bf16x8*)&Bs[wn + n * 16 + lr][kk + lh * 8];
#pragma unroll
      for (int m = 0; m < 4; ++m)
#pragma unroll
        for (int n = 0; n < 4; ++n)
          acc[m][n] = __builtin_amdgcn_mfma_f32_16x16x32_bf16(af[m], bfr[n], acc[m][n], 0, 0, 0);
    }
  }
#pragma unroll
  for (int m = 0; m < 4; ++m)
#pragma unroll
    for (int n = 0; n < 4; ++n) {
      const int col = n0 + wn + n * 16 + lr;
#pragma unroll
      for (int j = 0; j < 4; ++j)
        C[(size_t)(m0 + wm + m * 16 + lh * 4 + j) * ldc + col] = acc[m][n][j];
    }
}

__global__ __launch_bounds__(256) void k_gemm_nt_f32a(const float* __restrict__ A,
                                                      const short* __restrict__ B,
                                                      float* __restrict__ C,
                                                      int lda, int ldb, int ldc, int K) {
  __shared__ __align__(16) short As[128][64];
  __shared__ __align__(16) short Bs[128][64];
  const int t = threadIdx.x;
  const int w = t >> 6, l = t & 63;
  const int lr = l & 15, lh = l >> 4;
  const int m0 = blockIdx.y * 128, n0 = blockIdx.x * 128;
  const int wm = (w >> 1) * 64, wn = (w & 1) * 64;
  floatx4 acc[4][4] = {};
  for (int k0 = 0; k0 < K; k0 += 64) {
    __syncthreads();
#pragma unroll
    for (int i = 0; i < 4; ++i) {
      const int c = i * 256 + t;
      const int r = c >> 3, c8 = (c & 7) * 8;
      const float4 a0 = *(const float4*)&A[(size_t)(m0 + r) * lda + k0 + c8];
      const float4 a1 = *(const float4*)&A[(size_t)(m0 + r) * lda + k0 + c8 + 4];
      bf16x8 va;
      va[0] = f2bf(a0.x); va[1] = f2bf(a0.y); va[2] = f2bf(a0.z); va[3] = f2bf(a0.w);
      va[4] = f2bf(a1.x); va[5] = f2bf(a1.y); va[6] = f2bf(a1.z); va[7] = f2bf(a1.w);
      *(bf16x8*)&As[r][c8] = va;
      *(bf16x8*)&Bs[r][c8] = *(const bf16x8*)&B[(size_t)(n0 + r) * ldb + k0 + c8];
    }
    __syncthreads();
#pragma unroll
    for (int kk = 0; kk < 64; kk += 32) {
      bf16x8 af[4], bfr[4];
#pragma unroll
      for (int m = 0; m < 4; ++m) af[m] = *(const bf16x8*)&As[wm + m * 16 + lr][kk + lh * 8];
#pragma unroll
      for (int n = 0; n < 4; ++n) bfr[n] = *(const bf16x8*)&Bs[wn + n * 16 + lr][kk + lh * 8];
#pragma unroll
      for (int m = 0; m < 4; ++m)
#pragma unroll
        for (int n = 0; n < 4; ++n)
          acc[m][n] = __builtin_amdgcn_mfma_f32_16x16x32_bf16(af[m], bfr[n], acc[m][n], 0, 0, 0);
    }
  }
#pragma unroll
  for (int m = 0; m < 4; ++m)
#pragma unroll
    for (int n = 0; n < 4; ++n) {
      const int col = n0 + wn + n * 16 + lr;
#pragma unroll
      for (int j = 0; j < 4; ++j)
        C[(size_t)(m0 + wm + m * 16 + lh * 4 + j) * ldc + col] = acc[m][n][j];
    }
}

__global__ __launch_bounds__(256) void k_gumbel_softmax(float* __restrict__ S,
                                                        const float* __restrict__ U) {
  const int t = threadIdx.x;
  const int w = t >> 6, l = t & 63;
  const size_t base = (size_t)blockIdx.x * V_DIM + t * 8;
  const float4 s0 = *(const float4*)&S[base];
  const float4 s1 = *(const float4*)&S[base + 4];
  const float4 u0 = *(const float4*)&U[base];
  const float4 u1 = *(const float4*)&U[base + 4];
  float x[8];
  x[0] = s0.x - 2.f * __logf(-__logf(u0.x + 1e-10f) + 1e-10f);
  x[1] = s0.y - 2.f * __logf(-__logf(u0.y + 1e-10f) + 1e-10f);
  x[2] = s0.z - 2.f * __logf(-__logf(u0.z + 1e-10f) + 1e-10f);
  x[3] = s0.w - 2.f * __logf(-__logf(u0.w + 1e-10f) + 1e-10f);
  x[4] = s1.x - 2.f * __logf(-__logf(u1.x + 1e-10f) + 1e-10f);
  x[5] = s1.y - 2.f * __logf(-__logf(u1.y + 1e-10f) + 1e-10f);
  x[6] = s1.z - 2.f * __logf(-__logf(u1.z + 1e-10f) + 1e-10f);
  x[7] = s1.w - 2.f * __logf(-__logf(u1.w + 1e-10f) + 1e-10f);
  float lm = x[0];
#pragma unroll
  for (int i = 1; i < 8; ++i) lm = fmaxf(lm, x[i]);
  lm = wave_max(lm);
  __shared__ float redA[4], redB[4];
  if (l == 0) redA[w] = lm;
  __syncthreads();
  const float m = fmaxf(fmaxf(redA[0], redA[1]), fmaxf(redA[2], redA[3]));
  float p[8];
  float ls = 0.f;
#pragma unroll
  for (int i = 0; i < 8; ++i) { p[i] = __expf(x[i] - m); ls += p[i]; }
  ls = wave_sum(ls);
  if (l == 0) redB[w] = ls;
  __syncthreads();
  const float inv = 1.0f / (redB[0] + redB[1] + redB[2] + redB[3]);
  float4 o0 = make_float4(p[0] * inv, p[1] * inv, p[2] * inv, p[3] * inv);
  float4 o1 = make_float4(p[4] * inv, p[5] * inv, p[6] * inv, p[7] * inv);
  *(float4*)&S[base] = o0;
  *(float4*)&S[base + 4] = o1;
}

extern "C" void kernel_launch(void* const* d_in, const int* in_sizes, int n_in,
                              void* d_out, int out_size, void* d_ws, size_t ws_size,
                              hipStream_t stream) {
  const float* z = (const float*)d_in[0];
  const float* W = (const float*)d_in[1];
  const float* U = (const float*)d_in[2];
  float* tokens = (float*)d_out;                    // [N, V] f32
  float* zq = tokens + (size_t)N_ROWS * V_DIM;      // [N, E] f32
  short* zn = (short*)zq;                           // bf16 zn in z_q region

  short* embn = (short*)d_ws;                       // 4 MB
  short* embnT = embn + (size_t)V_DIM * E_DIM;      // 4 MB

  const size_t NEED = (size_t)V_DIM * E_DIM * 2 * 2     // embn + embnT
                    + (size_t)N_ROWS * 32 * 4           // partials (8 MB)
                    + (size_t)N_ROWS * 4                // invsum
                    + (size_t)N_ROWS * V_DIM * 2;       // P~ bf16 (256 MB)

  k_norm_emb<<<V_DIM, 256, 0, stream>>>(W, embn, embnT);
  k_norm_z<<<N_ROWS / 4, 256, 0, stream>>>(z, zn);

  if (ws_size >= NEED) {
    float* partials = (float*)(embnT + (size_t)V_DIM * E_DIM);
    float* invsum = partials + (size_t)N_ROWS * 32;
    short* Pb = (short*)(invsum + N_ROWS);
    // GEMM1 fused gumbel-exp: grid = (65536/256) * (2048/256) = 2048
    k_gemm8<E_DIM, 8, 0><<<2048, 512, 0, stream>>>(
        zn, embn, U, Pb, partials, nullptr, nullptr, nullptr, 2048 / 8);
    k_rowsum_inv<<<N_ROWS / 256, 256, 0, stream>>>(partials, invsum);
    // GEMM2 scaled + fused tokens write: grid = (65536/256) * (1024/256) = 1024
    k_gemm8<V_DIM, 4, 1><<<1024, 512, 0, stream>>>(
        Pb, embnT, nullptr, nullptr, nullptr, invsum, zq, tokens, 1024 / 8);
  } else {
    k_gemm_nt<<<dim3(V_DIM / 128, N_ROWS / 128), 256, 0, stream>>>(
        zn, embn, tokens, E_DIM, E_DIM, V_DIM, E_DIM);
    k_gumbel_softmax<<<N_ROWS, 256, 0, stream>>>(tokens, U);
    k_gemm_nt_f32a<<<dim3(E_DIM / 128, N_ROWS / 128), 256, 0, stream>>>(
        tokens, embnT, zq, V_DIM, V_DIM, E_DIM, V_DIM);
  }
}

// Round 9
// 1186.209 us; speedup vs baseline: 1.2015x; 1.2015x over previous
//
#include <hip/hip_runtime.h>
#include <hip/hip_bf16.h>
#include <stdint.h>

typedef short bf16x8 __attribute__((ext_vector_type(8)));
typedef float floatx4 __attribute__((ext_vector_type(4)));

#define N_ROWS 65536
#define V_DIM 2048
#define E_DIM 1024

__device__ __forceinline__ short f2bf(float x) {
  union { float f; uint32_t u; } c; c.f = x;
  uint32_t r = (c.u + 0x7FFFu + ((c.u >> 16) & 1u)) >> 16;
  return (short)(uint16_t)r;
}
__device__ __forceinline__ float bf16f(short b) {
  union { uint32_t u; float f; } c; c.u = ((uint32_t)(uint16_t)b) << 16;
  return c.f;
}

__device__ __forceinline__ float wave_sum(float v) {
#pragma unroll
  for (int o = 32; o > 0; o >>= 1) v += __shfl_xor(v, o);
  return v;
}
__device__ __forceinline__ float wave_max(float v) {
#pragma unroll
  for (int o = 32; o > 0; o >>= 1) v = fmaxf(v, __shfl_xor(v, o));
  return v;
}

__device__ __forceinline__ void gll16(const short* g, short* l) {
  __builtin_amdgcn_global_load_lds(
      (const __attribute__((address_space(1))) void*)g,
      (__attribute__((address_space(3))) void*)l, 16, 0, 0);
}

// fallback 128B-row swizzled fragment read
#define FRAG(base, R, c) \
  (*(const bf16x8*)((const char*)(base) + ((R) << 7) + (((((c) >> 3) ^ ((R) & 7))) << 4)))

// ---------------- normalize emb rows -> bf16 embn [V][E] and embnT [E][V] ----
__global__ __launch_bounds__(256) void k_norm_emb(const float* __restrict__ W,
                                                  short* __restrict__ embn,
                                                  short* __restrict__ embnT) {
  const int v = blockIdx.x;
  const int t = threadIdx.x;
  const int w = t >> 6, l = t & 63;
  const float4 val = *(const float4*)&W[(size_t)v * E_DIM + t * 4];
  float ss = val.x * val.x + val.y * val.y + val.z * val.z + val.w * val.w;
  ss = wave_sum(ss);
  __shared__ float red[4];
  if (l == 0) red[w] = ss;
  __syncthreads();
  ss = red[0] + red[1] + red[2] + red[3];
  const float inv = 1.0f / fmaxf(sqrtf(ss), 1e-12f);
  short4 o;
  o.x = f2bf(val.x * inv);
  o.y = f2bf(val.y * inv);
  o.z = f2bf(val.z * inv);
  o.w = f2bf(val.w * inv);
  *(short4*)&embn[(size_t)v * E_DIM + t * 4] = o;
  embnT[(size_t)(t * 4 + 0) * V_DIM + v] = o.x;
  embnT[(size_t)(t * 4 + 1) * V_DIM + v] = o.y;
  embnT[(size_t)(t * 4 + 2) * V_DIM + v] = o.z;
  embnT[(size_t)(t * 4 + 3) * V_DIM + v] = o.w;
}

// ---------------- normalize z rows, fold in kappa_q/T, -> bf16 zn [N][E] -----
__global__ __launch_bounds__(256) void k_norm_z(const float* __restrict__ Z,
                                                short* __restrict__ zn) {
  const int w = threadIdx.x >> 6, l = threadIdx.x & 63;
  const int row = blockIdx.x * 4 + w;
  const float* zr = Z + (size_t)row * E_DIM;
  float4 v[4];
  float ss = 0.f;
#pragma unroll
  for (int i = 0; i < 4; ++i) {
    v[i] = *(const float4*)&zr[(i * 64 + l) * 4];
    ss += v[i].x * v[i].x + v[i].y * v[i].y + v[i].z * v[i].z + v[i].w * v[i].w;
  }
  ss = wave_sum(ss);
  const float SCALE = 2.0f * (expf(-2.995732273553991f) + 1.0f);  // kappa_q / T
  const float inv = SCALE / fmaxf(sqrtf(ss), 1e-12f);
  short* zo = zn + (size_t)row * E_DIM;
#pragma unroll
  for (int i = 0; i < 4; ++i) {
    short4 o;
    o.x = f2bf(v[i].x * inv);
    o.y = f2bf(v[i].y * inv);
    o.z = f2bf(v[i].z * inv);
    o.w = f2bf(v[i].w * inv);
    *(short4*)&zo[(i * 64 + l) * 4] = o;
  }
}

// =============== FAST PATH: 128x128 tile, 4 waves, BK=32, 4-slot ring, counted
// vmcnt(4), look-ahead frag reads.  64 KiB LDS -> 2 blocks/CU: inter-block slip
// hides drains/latency (m97/m114 mechanism).
// EPI 0: gumbel-exp -> Pb bf16 + partials[N][32].  EPI 1: invsum-scaled -> C.
template <int KDIM, int NBX, int EPI>
__global__ __launch_bounds__(256, 4) void k_gemm4(
    const short* __restrict__ A, const short* __restrict__ B,
    const float* __restrict__ U, short* __restrict__ Pb,
    float* __restrict__ partials, const float* __restrict__ invsum,
    float* __restrict__ C, int cpx) {
  __shared__ __align__(16) short Sm[32768];  // A ring: 4 x 8KB; B ring at byte 32768
  const int NT = KDIM / 32;
  const int tid = threadIdx.x;
  const int wv = tid >> 6, lane = tid & 63;
  const int lr = lane & 15, lh = lane >> 4;
  const int wm = (wv >> 1) * 64, wn = (wv & 1) * 64;  // 2x2 wave grid
  // XCD-chunked bijective swizzle (grid multiple of 8)
  const int d = blockIdx.x;
  const int L = (d & 7) * cpx + (d >> 3);
  const int by = L / NBX, bx = L % NBX;
  const int m0 = by * 128, n0 = bx * 128;
  // staging: LDS rows srow (chunk 0) and srow+64 (chunk 1); linear dest;
  // pre-swizzled global granule, f(R) = (R ^ (R>>2)) & 3
  const int sg = (((lane & 3) ^ ((lane >> 2) & 3) ^ ((lane >> 4) & 3)) << 3);
  const int srow = wv * 16 + (lane >> 2);
  const short* gA = A + (size_t)(m0 + srow) * KDIM + sg;
  const short* gB = B + (size_t)(n0 + srow) * KDIM + sg;
  // fragment read slot = lh ^ f(R); f(R) = (lr ^ (lr>>2)) & 3 for all frag rows
  const int fslot = lh ^ ((lr ^ (lr >> 2)) & 3);
  const int aoff = (wm + lr) * 64 + fslot * 16;  // bytes within A slot
  const int boff = (wn + lr) * 64 + fslot * 16;  // bytes within B slot

  bf16x8 af[4], bfr[4];
  floatx4 acc[4][4] = {};

#define STAGE(KT)                                                                   \
  {                                                                                 \
    short* An_ = Sm + ((KT) & 3) * 4096;                                            \
    short* Bn_ = Sm + 16384 + ((KT) & 3) * 4096;                                    \
    const size_t kc_ = (size_t)(KT) * 32;                                           \
    gll16(gA + kc_, An_ + wv * 512);                                                \
    gll16(gA + (size_t)64 * KDIM + kc_, An_ + 2048 + wv * 512);                     \
    gll16(gB + kc_, Bn_ + wv * 512);                                                \
    gll16(gB + (size_t)64 * KDIM + kc_, Bn_ + 2048 + wv * 512);                     \
  }
#define RD_AB(KT)                                                                   \
  {                                                                                 \
    const char* Ab_ = (const char*)Sm + ((KT) & 3) * 8192;                          \
    const char* Bb_ = (const char*)Sm + 32768 + ((KT) & 3) * 8192;                  \
    _Pragma("unroll")                                                               \
    for (int n = 0; n < 4; ++n) bfr[n] = *(const bf16x8*)(Bb_ + boff + n * 1024);   \
    _Pragma("unroll")                                                               \
    for (int i = 0; i < 4; ++i) af[i] = *(const bf16x8*)(Ab_ + aoff + i * 1024);    \
  }
#define MF                                                                          \
  __builtin_amdgcn_s_setprio(1);                                                    \
  _Pragma("unroll")                                                                 \
  for (int i = 0; i < 4; ++i) {                                                     \
    _Pragma("unroll")                                                               \
    for (int n = 0; n < 4; ++n)                                                     \
      acc[i][n] = __builtin_amdgcn_mfma_f32_16x16x32_bf16(af[i], bfr[n], acc[i][n], 0, 0, 0); \
  }                                                                                 \
  __builtin_amdgcn_s_setprio(0);

  // prologue: stage tiles 0 and 1 (8 loads), wait for tile 0 (leave 4)
  STAGE(0);
  STAGE(1);
  asm volatile("s_waitcnt vmcnt(4)" ::: "memory");
  __builtin_amdgcn_s_barrier();
  __builtin_amdgcn_sched_barrier(0);
  RD_AB(0);

#pragma unroll 2
  for (int kt = 0; kt < NT - 2; ++kt) {
    STAGE(kt + 2);       // 4 loads into slot (kt+2)&3 (last read 2 barriers ago)
    MF;                  // frags of tile kt, read one barrier ago
    asm volatile("s_waitcnt vmcnt(4)" ::: "memory");  // tile kt+1's loads landed
    __builtin_amdgcn_s_barrier();
    __builtin_amdgcn_sched_barrier(0);
    RD_AB(kt + 1);       // look-ahead: used next iteration
  }
  // tile NT-2
  MF;
  asm volatile("s_waitcnt vmcnt(0)" ::: "memory");
  __builtin_amdgcn_s_barrier();
  __builtin_amdgcn_sched_barrier(0);
  RD_AB(NT - 1);
  // tile NT-1
  MF;
#undef STAGE
#undef RD_AB
#undef MF

  const int gr0 = m0 + wm + lh * 4;
  const int gc0 = n0 + wn + lr;
  if (EPI == 0) {
    float rs[4][4] = {};
#pragma unroll
    for (int m = 0; m < 4; ++m)
#pragma unroll
      for (int n = 0; n < 4; ++n) {
        const int col = gc0 + n * 16;
#pragma unroll
        for (int j = 0; j < 4; ++j) {
          const int row = gr0 + m * 16 + j;
          const size_t idx = (size_t)row * V_DIM + col;
          const float u = U[idx];
          const float e = __expf(acc[m][n][j] - 2.f * __logf(-__logf(u + 1e-10f) + 1e-10f));
          const short eb = f2bf(e);
          Pb[idx] = eb;
          rs[m][j] += bf16f(eb);
        }
      }
#pragma unroll
    for (int m = 0; m < 4; ++m)
#pragma unroll
      for (int j = 0; j < 4; ++j) {
        float s = rs[m][j];
        s += __shfl_xor(s, 1); s += __shfl_xor(s, 2);
        s += __shfl_xor(s, 4); s += __shfl_xor(s, 8);
        if (lr == 0)
          partials[(size_t)(gr0 + m * 16 + j) * 32 + bx * 2 + (wv & 1)] = s;
      }
  } else {
#pragma unroll
    for (int m = 0; m < 4; ++m)
#pragma unroll
      for (int j = 0; j < 4; ++j) {
        const int row = gr0 + m * 16 + j;
        const float s = invsum[row];
#pragma unroll
        for (int n = 0; n < 4; ++n)
          C[(size_t)row * E_DIM + gc0 + n * 16] = acc[m][n][j] * s;
      }
  }
}

// invsum[r] = 1 / sum(partials[r][0..32))
__global__ __launch_bounds__(256) void k_rowsum_inv(const float* __restrict__ partials,
                                                    float* __restrict__ invsum) {
  const int r = blockIdx.x * 256 + threadIdx.x;
  const float4* p = (const float4*)&partials[(size_t)r * 32];
  float s = 0.f;
#pragma unroll
  for (int i = 0; i < 8; ++i) { float4 v = p[i]; s += v.x + v.y + v.z + v.w; }
  invsum[r] = 1.f / s;
}

// tokens f32 = bf16(P~) * invsum[row]
__global__ __launch_bounds__(256) void k_token_norm(const short* __restrict__ Pb,
                                                    const float* __restrict__ invsum,
                                                    float* __restrict__ tokens) {
  const size_t stride = (size_t)gridDim.x * 256 * 8;
  for (size_t i = ((size_t)blockIdx.x * 256 + threadIdx.x) * 8;
       i < (size_t)N_ROWS * V_DIM; i += stride) {
    const float s = invsum[i >> 11];
    const bf16x8 v = *(const bf16x8*)&Pb[i];
    float4 o0, o1;
    o0.x = bf16f(v[0]) * s; o0.y = bf16f(v[1]) * s;
    o0.z = bf16f(v[2]) * s; o0.w = bf16f(v[3]) * s;
    o1.x = bf16f(v[4]) * s; o1.y = bf16f(v[5]) * s;
    o1.z = bf16f(v[6]) * s; o1.w = bf16f(v[7]) * s;
    *(float4*)&tokens[i] = o0;
    *(float4*)&tokens[i + 4] = o1;
  }
}

// =============== FALLBACK PATH (round-1, known-correct) ======================
__global__ __launch_bounds__(256) void k_gemm_nt(const short* __restrict__ A,
                                                 const short* __restrict__ B,
                                                 float* __restrict__ C,
                                                 int lda, int ldb, int ldc, int K) {
  __shared__ __align__(16) short As[128][64];
  __shared__ __align__(16) short Bs[128][64];
  const int t = threadIdx.x;
  const int w = t >> 6, l = t & 63;
  const int lr = l & 15, lh = l >> 4;
  const int m0 = blockIdx.y * 128, n0 = blockIdx.x * 128;
  const int wm = (w >> 1) * 64, wn = (w & 1) * 64;
  floatx4 acc[4][4] = {};
  for (int k0 = 0; k0 < K; k0 += 64) {
    __syncthreads();
#pragma unroll
    for (int i = 0; i < 4; ++i) {
      const int c = i * 256 + t;
      const int r = c >> 3, c8 = (c & 7) * 8;
      *(bf16x8*)&As[r][c8] = *(const bf16x8*)&A[(size_t)(m0 + r) * lda + k0 + c8];
      *(bf16x8*)&Bs[r][c8] = *(const bf16x8*)&B[(size_t)(n0 + r) * ldb + k0 + c8];
    }
    __syncthreads();
#pragma unroll
    for (int kk = 0; kk < 64; kk += 32) {
      bf16x8 af[4], bfr[4];
#pragma unroll
      for (int m = 0; m < 4; ++m) af[m] = *(const bf16x8*)&As[wm + m * 16 + lr][kk + lh * 8];
#pragma unroll
      for (int n = 0; n < 4; ++n) bfr[n] = *(const bf16x8*)&Bs[wn + n * 16 + lr][kk + lh * 8];
#pragma unroll
      for (int m = 0; m < 4; ++m)
#pragma unroll
        for (int n = 0; n < 4; ++n)
          acc[m][n] = __builtin_amdgcn_mfma_f32_16x16x32_bf16(af[m], bfr[n], acc[m][n], 0, 0, 0);
    }
  }
#pragma unroll
  for (int m = 0; m < 4; ++m)
#pragma unroll
    for (int n = 0; n < 4; ++n) {
      const int col = n0 + wn + n * 16 + lr;
#pragma unroll
      for (int j = 0; j < 4; ++j)
        C[(size_t)(m0 + wm + m * 16 + lh * 4 + j) * ldc + col] = acc[m][n][j];
    }
}

__global__ __launch_bounds__(256) void k_gemm_nt_f32a(const float* __restrict__ A,
                                                      const short* __restrict__ B,
                                                      float* __restrict__ C,
                                                      int lda, int ldb, int ldc, int K) {
  __shared__ __align__(16) short As[128][64];
  __shared__ __align__(16) short Bs[128][64];
  const int t = threadIdx.x;
  const int w = t >> 6, l = t & 63;
  const int lr = l & 15, lh = l >> 4;
  const int m0 = blockIdx.y * 128, n0 = blockIdx.x * 128;
  const int wm = (w >> 1) * 64, wn = (w & 1) * 64;
  floatx4 acc[4][4] = {};
  for (int k0 = 0; k0 < K; k0 += 64) {
    __syncthreads();
#pragma unroll
    for (int i = 0; i < 4; ++i) {
      const int c = i * 256 + t;
      const int r = c >> 3, c8 = (c & 7) * 8;
      const float4 a0 = *(const float4*)&A[(size_t)(m0 + r) * lda + k0 + c8];
      const float4 a1 = *(const float4*)&A[(size_t)(m0 + r) * lda + k0 + c8 + 4];
      bf16x8 va;
      va[0] = f2bf(a0.x); va[1] = f2bf(a0.y); va[2] = f2bf(a0.z); va[3] = f2bf(a0.w);
      va[4] = f2bf(a1.x); va[5] = f2bf(a1.y); va[6] = f2bf(a1.z); va[7] = f2bf(a1.w);
      *(bf16x8*)&As[r][c8] = va;
      *(bf16x8*)&Bs[r][c8] = *(const bf16x8*)&B[(size_t)(n0 + r) * ldb + k0 + c8];
    }
    __syncthreads();
#pragma unroll
    for (int kk = 0; kk < 64; kk += 32) {
      bf16x8 af[4], bfr[4];
#pragma unroll
      for (int m = 0; m < 4; ++m) af[m] = *(const bf16x8*)&As[wm + m * 16 + lr][kk + lh * 8];
#pragma unroll
      for (int n = 0; n < 4; ++n) bfr[n] = *(const bf16x8*)&Bs[wn + n * 16 + lr][kk + lh * 8];
#pragma unroll
      for (int m = 0; m < 4; ++m)
#pragma unroll
        for (int n = 0; n < 4; ++n)
          acc[m][n] = __builtin_amdgcn_mfma_f32_16x16x32_bf16(af[m], bfr[n], acc[m][n], 0, 0, 0);
    }
  }
#pragma unroll
  for (int m = 0; m < 4; ++m)
#pragma unroll
    for (int n = 0; n < 4; ++n) {
      const int col = n0 + wn + n * 16 + lr;
#pragma unroll
      for (int j = 0; j < 4; ++j)
        C[(size_t)(m0 + wm + m * 16 + lh * 4 + j) * ldc + col] = acc[m][n][j];
    }
}

__global__ __launch_bounds__(256) void k_gumbel_softmax(float* __restrict__ S,
                                                        const float* __restrict__ U) {
  const int t = threadIdx.x;
  const int w = t >> 6, l = t & 63;
  const size_t base = (size_t)blockIdx.x * V_DIM + t * 8;
  const float4 s0 = *(const float4*)&S[base];
  const float4 s1 = *(const float4*)&S[base + 4];
  const float4 u0 = *(const float4*)&U[base];
  const float4 u1 = *(const float4*)&U[base + 4];
  float x[8];
  x[0] = s0.x - 2.f * __logf(-__logf(u0.x + 1e-10f) + 1e-10f);
  x[1] = s0.y - 2.f * __logf(-__logf(u0.y + 1e-10f) + 1e-10f);
  x[2] = s0.z - 2.f * __logf(-__logf(u0.z + 1e-10f) + 1e-10f);
  x[3] = s0.w - 2.f * __logf(-__logf(u0.w + 1e-10f) + 1e-10f);
  x[4] = s1.x - 2.f * __logf(-__logf(u1.x + 1e-10f) + 1e-10f);
  x[5] = s1.y - 2.f * __logf(-__logf(u1.y + 1e-10f) + 1e-10f);
  x[6] = s1.z - 2.f * __logf(-__logf(u1.z + 1e-10f) + 1e-10f);
  x[7] = s1.w - 2.f * __logf(-__logf(u1.w + 1e-10f) + 1e-10f);
  float lm = x[0];
#pragma unroll
  for (int i = 1; i < 8; ++i) lm = fmaxf(lm, x[i]);
  lm = wave_max(lm);
  __shared__ float redA[4], redB[4];
  if (l == 0) redA[w] = lm;
  __syncthreads();
  const float m = fmaxf(fmaxf(redA[0], redA[1]), fmaxf(redA[2], redA[3]));
  float p[8];
  float ls = 0.f;
#pragma unroll
  for (int i = 0; i < 8; ++i) { p[i] = __expf(x[i] - m); ls += p[i]; }
  ls = wave_sum(ls);
  if (l == 0) redB[w] = ls;
  __syncthreads();
  const float inv = 1.0f / (redB[0] + redB[1] + redB[2] + redB[3]);
  float4 o0 = make_float4(p[0] * inv, p[1] * inv, p[2] * inv, p[3] * inv);
  float4 o1 = make_float4(p[4] * inv, p[5] * inv, p[6] * inv, p[7] * inv);
  *(float4*)&S[base] = o0;
  *(float4*)&S[base + 4] = o1;
}

extern "C" void kernel_launch(void* const* d_in, const int* in_sizes, int n_in,
                              void* d_out, int out_size, void* d_ws, size_t ws_size,
                              hipStream_t stream) {
  const float* z = (const float*)d_in[0];
  const float* W = (const float*)d_in[1];
  const float* U = (const float*)d_in[2];
  float* tokens = (float*)d_out;                    // [N, V] f32
  float* zq = tokens + (size_t)N_ROWS * V_DIM;      // [N, E] f32
  short* zn = (short*)zq;                           // bf16 zn in z_q region

  short* embn = (short*)d_ws;                       // 4 MB
  short* embnT = embn + (size_t)V_DIM * E_DIM;      // 4 MB

  const size_t NEED = (size_t)V_DIM * E_DIM * 2 * 2     // embn + embnT
                    + (size_t)N_ROWS * 32 * 4           // partials (8 MB)
                    + (size_t)N_ROWS * 4                // invsum
                    + (size_t)N_ROWS * V_DIM * 2;       // P~ bf16 (256 MB)

  k_norm_emb<<<V_DIM, 256, 0, stream>>>(W, embn, embnT);
  k_norm_z<<<N_ROWS / 4, 256, 0, stream>>>(z, zn);

  if (ws_size >= NEED) {
    float* partials = (float*)(embnT + (size_t)V_DIM * E_DIM);
    float* invsum = partials + (size_t)N_ROWS * 32;
    short* Pb = (short*)(invsum + N_ROWS);
    // GEMM1 fused gumbel-exp: grid = (65536/128) * (2048/128) = 512*16 = 8192
    k_gemm4<E_DIM, 16, 0><<<8192, 256, 0, stream>>>(
        zn, embn, U, Pb, partials, nullptr, nullptr, 8192 / 8);
    k_rowsum_inv<<<N_ROWS / 256, 256, 0, stream>>>(partials, invsum);
    k_token_norm<<<2048, 256, 0, stream>>>(Pb, invsum, tokens);
    // GEMM2 scaled: grid = (65536/128) * (1024/128) = 512*8 = 4096
    k_gemm4<V_DIM, 8, 1><<<4096, 256, 0, stream>>>(
        Pb, embnT, nullptr, nullptr, nullptr, invsum, zq, 4096 / 8);
  } else {
    k_gemm_nt<<<dim3(V_DIM / 128, N_ROWS / 128), 256, 0, stream>>>(
        zn, embn, tokens, E_DIM, E_DIM, V_DIM, E_DIM);
    k_gumbel_softmax<<<N_ROWS, 256, 0, stream>>>(tokens, U);
    k_gemm_nt_f32a<<<dim3(E_DIM / 128, N_ROWS / 128), 256, 0, stream>>>(
        tokens, embnT, zq, V_DIM, V_DIM, E_DIM, V_DIM);
  }
}

// Round 10
// 1039.317 us; speedup vs baseline: 1.3713x; 1.1413x over previous
//
#include <hip/hip_runtime.h>
#include <hip/hip_bf16.h>
#include <stdint.h>

typedef short bf16x8 __attribute__((ext_vector_type(8)));
typedef float floatx4 __attribute__((ext_vector_type(4)));

#define N_ROWS 65536
#define V_DIM 2048
#define E_DIM 1024

__device__ __forceinline__ short f2bf(float x) {
  union { float f; uint32_t u; } c; c.f = x;
  uint32_t r = (c.u + 0x7FFFu + ((c.u >> 16) & 1u)) >> 16;
  return (short)(uint16_t)r;
}
__device__ __forceinline__ float bf16f(short b) {
  union { uint32_t u; float f; } c; c.u = ((uint32_t)(uint16_t)b) << 16;
  return c.f;
}

__device__ __forceinline__ float wave_sum(float v) {
#pragma unroll
  for (int o = 32; o > 0; o >>= 1) v += __shfl_xor(v, o);
  return v;
}
__device__ __forceinline__ float wave_max(float v) {
#pragma unroll
  for (int o = 32; o > 0; o >>= 1) v = fmaxf(v, __shfl_xor(v, o));
  return v;
}

__device__ __forceinline__ void gll16(const short* g, short* l) {
  __builtin_amdgcn_global_load_lds(
      (const __attribute__((address_space(1))) void*)g,
      (__attribute__((address_space(3))) void*)l, 16, 0, 0);
}

// fallback 128B-row swizzled fragment read
#define FRAG(base, R, c) \
  (*(const bf16x8*)((const char*)(base) + ((R) << 7) + (((((c) >> 3) ^ ((R) & 7))) << 4)))

// ---------------- normalize emb rows -> bf16 embn [V][E] and embnT [E][V] ----
__global__ __launch_bounds__(256) void k_norm_emb(const float* __restrict__ W,
                                                  short* __restrict__ embn,
                                                  short* __restrict__ embnT) {
  const int v = blockIdx.x;
  const int t = threadIdx.x;
  const int w = t >> 6, l = t & 63;
  const float4 val = *(const float4*)&W[(size_t)v * E_DIM + t * 4];
  float ss = val.x * val.x + val.y * val.y + val.z * val.z + val.w * val.w;
  ss = wave_sum(ss);
  __shared__ float red[4];
  if (l == 0) red[w] = ss;
  __syncthreads();
  ss = red[0] + red[1] + red[2] + red[3];
  const float inv = 1.0f / fmaxf(sqrtf(ss), 1e-12f);
  short4 o;
  o.x = f2bf(val.x * inv);
  o.y = f2bf(val.y * inv);
  o.z = f2bf(val.z * inv);
  o.w = f2bf(val.w * inv);
  *(short4*)&embn[(size_t)v * E_DIM + t * 4] = o;
  embnT[(size_t)(t * 4 + 0) * V_DIM + v] = o.x;
  embnT[(size_t)(t * 4 + 1) * V_DIM + v] = o.y;
  embnT[(size_t)(t * 4 + 2) * V_DIM + v] = o.z;
  embnT[(size_t)(t * 4 + 3) * V_DIM + v] = o.w;
}

// ---------------- normalize z rows, fold in kappa_q/T, -> bf16 zn [N][E] -----
__global__ __launch_bounds__(256) void k_norm_z(const float* __restrict__ Z,
                                                short* __restrict__ zn) {
  const int w = threadIdx.x >> 6, l = threadIdx.x & 63;
  const int row = blockIdx.x * 4 + w;
  const float* zr = Z + (size_t)row * E_DIM;
  float4 v[4];
  float ss = 0.f;
#pragma unroll
  for (int i = 0; i < 4; ++i) {
    v[i] = *(const float4*)&zr[(i * 64 + l) * 4];
    ss += v[i].x * v[i].x + v[i].y * v[i].y + v[i].z * v[i].z + v[i].w * v[i].w;
  }
  ss = wave_sum(ss);
  const float SCALE = 2.0f * (expf(-2.995732273553991f) + 1.0f);  // kappa_q / T
  const float inv = SCALE / fmaxf(sqrtf(ss), 1e-12f);
  short* zo = zn + (size_t)row * E_DIM;
#pragma unroll
  for (int i = 0; i < 4; ++i) {
    short4 o;
    o.x = f2bf(v[i].x * inv);
    o.y = f2bf(v[i].y * inv);
    o.z = f2bf(v[i].z * inv);
    o.w = f2bf(v[i].w * inv);
    *(short4*)&zo[(i * 64 + l) * 4] = o;
  }
}

// =============== FAST PATH: 256x256 tile, BK=32, 4-buffer ring, counted vmcnt,
// two fine phases per K-tile (R4 form, measured best).
// EPI 0: gumbel-exp with epilogue-pipelined U loads -> Pb bf16 + partials.
// EPI 1: col-major block order (embnT L2-residency); invsum-scaled -> C; then
//        tokens tail: re-read own L2-hot Pb quarter, write f32 tokens slice.
template <int KDIM, int NBX, int EPI>
__global__ __launch_bounds__(512, 2) void k_gemm8(
    const short* __restrict__ A, const short* __restrict__ B,
    const float* __restrict__ U, short* __restrict__ Pb,
    float* __restrict__ partials, const float* __restrict__ invsum,
    float* __restrict__ C, float* __restrict__ tokens, int cpx) {
  __shared__ __align__(16) short Sm[65536];  // A ring: 4 x 16KB at byte 0; B ring at byte 65536
  const int NT = KDIM / 32;
  const int tid = threadIdx.x;
  const int wv = tid >> 6, lane = tid & 63;
  const int lr = lane & 15, lh = lane >> 4;
  const int wr = wv >> 2, wc = wv & 3;  // 2x4 wave grid
  // XCD-chunked bijective swizzle (grid multiple of 8)
  const int d = blockIdx.x;
  const int L = (d & 7) * cpx + (d >> 3);
  // EPI0: row-major (zn panel shared by consecutive L).  EPI1: col-major
  // (one embnT panel per XCD stays L2-resident while Pb streams).
  const int by = (EPI == 0) ? (L / NBX) : (L & 255);
  const int bx = (EPI == 0) ? (L % NBX) : (L >> 8);
  const int m0 = by * 256, n0 = bx * 256;
  // staging: LDS row R_w = q*128 + wv*16 + (lane>>2); linear dest; source granule
  // pre-swizzled: kg = (lane&3) ^ f(R_w), f(R) = (R ^ (R>>2)) & 3
  const int sg = (((lane & 3) ^ ((lane >> 2) & 3) ^ ((lane >> 4) & 3)) << 3);
  const int srow = wv * 16 + (lane >> 2);
  const short* gA = A + (size_t)(m0 + srow) * KDIM + sg;
  const short* gB = B + (size_t)(n0 + srow) * KDIM + sg;
  // fragment read: slot = lh ^ f(R); f(R) = (lr ^ (lr>>2)) & 3 for all frag rows
  const int fslot = lh ^ ((lr ^ (lr >> 2)) & 3);
  const int aoff = wr * 8192 + lr * 64 + fslot * 16;  // bytes within A buffer
  const int boff = wc * 4096 + lr * 64 + fslot * 16;  // bytes within B buffer

  // prologue: stage tiles 0 and 1
#pragma unroll
  for (int t = 0; t < 2; ++t) {
#pragma unroll
    for (int q = 0; q < 2; ++q) {
      gll16(gA + (size_t)(q * 128) * KDIM + t * 32, Sm + t * 8192 + q * 4096 + wv * 512);
      gll16(gB + (size_t)(q * 128) * KDIM + t * 32, Sm + 32768 + t * 8192 + q * 4096 + wv * 512);
    }
  }
  asm volatile("s_waitcnt vmcnt(4)" ::: "memory");
  __builtin_amdgcn_s_barrier();
  __builtin_amdgcn_sched_barrier(0);

  floatx4 acc[8][4] = {};

#define DO_TILE(KT, STAGE, VMN)                                                     \
  {                                                                                 \
    const int cb_ = (KT) & 3;                                                       \
    const char* Ab_ = (const char*)Sm + cb_ * 16384;                                \
    const char* Bb_ = (const char*)Sm + 65536 + cb_ * 16384;                        \
    short* An_ = Sm + (((KT) + 2) & 3) * 8192;                                      \
    short* Bn_ = Sm + 32768 + (((KT) + 2) & 3) * 8192;                              \
    const size_t kc_ = (size_t)((KT) + 2) * 32;                                     \
    bf16x8 bfr[4], af[4];                                                           \
    /* ---------- phase A: B-frags + A-frags(m0..3) | stage A halves ---------- */ \
    _Pragma("unroll")                                                               \
    for (int n = 0; n < 4; ++n) bfr[n] = *(const bf16x8*)(Bb_ + boff + n * 1024);   \
    _Pragma("unroll")                                                               \
    for (int i = 0; i < 4; ++i) af[i] = *(const bf16x8*)(Ab_ + aoff + i * 1024);    \
    if (STAGE) {                                                                    \
      gll16(gA + kc_, An_ + wv * 512);                                              \
      gll16(gA + (size_t)128 * KDIM + kc_, An_ + 4096 + wv * 512);                  \
    }                                                                               \
    __builtin_amdgcn_s_barrier();                                                   \
    asm volatile("s_waitcnt lgkmcnt(0)" ::: "memory");                              \
    __builtin_amdgcn_sched_barrier(0);                                              \
    __builtin_amdgcn_s_setprio(1);                                                  \
    _Pragma("unroll")                                                               \
    for (int i = 0; i < 4; ++i) {                                                   \
      _Pragma("unroll")                                                             \
      for (int n = 0; n < 4; ++n)                                                   \
        acc[i][n] =                                                                 \
            __builtin_amdgcn_mfma_f32_16x16x32_bf16(af[i], bfr[n], acc[i][n], 0, 0, 0); \
    }                                                                               \
    __builtin_amdgcn_s_setprio(0);                                                  \
    __builtin_amdgcn_s_barrier();                                                   \
    /* ---------- phase B: A-frags(m4..7) | stage B halves -------------------- */ \
    _Pragma("unroll")                                                               \
    for (int i = 0; i < 4; ++i)                                                     \
      af[i] = *(const bf16x8*)(Ab_ + aoff + 4096 + i * 1024);                       \
    if (STAGE) {                                                                    \
      gll16(gB + kc_, Bn_ + wv * 512);                                              \
      gll16(gB + (size_t)128 * KDIM + kc_, Bn_ + 4096 + wv * 512);                  \
    }                                                                               \
    __builtin_amdgcn_s_barrier();                                                   \
    asm volatile("s_waitcnt lgkmcnt(0)" ::: "memory");                              \
    __builtin_amdgcn_sched_barrier(0);                                              \
    __builtin_amdgcn_s_setprio(1);                                                  \
    _Pragma("unroll")                                                               \
    for (int i = 0; i < 4; ++i) {                                                   \
      _Pragma("unroll")                                                             \
      for (int n = 0; n < 4; ++n)                                                   \
        acc[4 + i][n] =                                                             \
            __builtin_amdgcn_mfma_f32_16x16x32_bf16(af[i], bfr[n], acc[4 + i][n], 0, 0, 0); \
    }                                                                               \
    __builtin_amdgcn_s_setprio(0);                                                  \
    asm volatile("s_waitcnt vmcnt(" #VMN ")" ::: "memory");                         \
    __builtin_amdgcn_s_barrier();                                                   \
    __builtin_amdgcn_sched_barrier(0);                                              \
  }

  for (int kt = 0; kt < NT - 2; ++kt) DO_TILE(kt, 1, 4);
  DO_TILE(NT - 2, 0, 0);
  DO_TILE(NT - 1, 0, 0);
#undef DO_TILE

  const int gr0 = m0 + wr * 128 + lh * 4;
  const int gc0 = n0 + wc * 64 + lr;
  if (EPI == 0) {
    const float* Ug = U + (size_t)gr0 * V_DIM + gc0;
    float rs[8][4] = {};
    float u01[32], u23[32], u45[32], u67[32];
// U prefetch: rows m=2P..2P+1 of this thread's epilogue tile, 32 scalar loads
#define UPREF(arr, P)                                                               \
    {                                                                               \
      _Pragma("unroll")                                                             \
      for (int mm = 0; mm < 2; ++mm)                                                \
        _Pragma("unroll")                                                           \
        for (int n = 0; n < 4; ++n)                                                 \
          _Pragma("unroll")                                                         \
          for (int j = 0; j < 4; ++j)                                               \
            arr[mm * 16 + n * 4 + j] =                                              \
                Ug[(size_t)(((2 * (P) + mm) * 16 + j)) * V_DIM + n * 16];           \
    }
#define EPI_PAIR(P, arr)                                                            \
    _Pragma("unroll")                                                               \
    for (int mm = 0; mm < 2; ++mm) {                                                \
      const int m = 2 * (P) + mm;                                                   \
      _Pragma("unroll")                                                             \
      for (int n = 0; n < 4; ++n) {                                                 \
        const int col = gc0 + n * 16;                                               \
        _Pragma("unroll")                                                           \
        for (int j = 0; j < 4; ++j) {                                               \
          const int row = gr0 + m * 16 + j;                                         \
          const size_t idx = (size_t)row * V_DIM + col;                             \
          const float u = arr[mm * 16 + n * 4 + j];                                 \
          const float e = __expf(acc[m][n][j] -                                     \
                                 2.f * __logf(-__logf(u + 1e-10f) + 1e-10f));       \
          const short eb = f2bf(e);                                                 \
          Pb[idx] = eb;                                                             \
          rs[m][j] += bf16f(eb);                                                    \
        }                                                                           \
      }                                                                             \
    }
    UPREF(u01, 0);
    UPREF(u23, 1);
    UPREF(u45, 2);
    EPI_PAIR(0, u01);
    UPREF(u67, 3);
    EPI_PAIR(1, u23);
    EPI_PAIR(2, u45);
    EPI_PAIR(3, u67);
#undef UPREF
#undef EPI_PAIR
#pragma unroll
    for (int m = 0; m < 8; ++m)
#pragma unroll
      for (int j = 0; j < 4; ++j) {
        float s = rs[m][j];
        s += __shfl_xor(s, 1); s += __shfl_xor(s, 2);
        s += __shfl_xor(s, 4); s += __shfl_xor(s, 8);
        if (lr == 0)
          partials[(size_t)(gr0 + m * 16 + j) * 32 + bx * 4 + wc] = s;
      }
  } else {
#pragma unroll
    for (int m = 0; m < 8; ++m)
#pragma unroll
      for (int j = 0; j < 4; ++j) {
        const int row = gr0 + m * 16 + j;
        const float s = invsum[row];
#pragma unroll
        for (int n = 0; n < 4; ++n)
          C[(size_t)row * E_DIM + gc0 + n * 16] = acc[m][n][j] * s;
      }
    // ---- tokens tail: rows m0..m0+255, cols bx*512..bx*512+511 ----
    // Pb slice is L2-hot (this block staged exactly these rows in the mainloop).
    const int tcol0 = bx * 512;
    const int rowoff = tid >> 7;        // 0..3
    const int coff = (tid & 127) * 4;   // 0..508, 16B/lane stores, 8B/lane loads
    for (int it = 0; it < 64; ++it) {
      const int row = m0 + it * 4 + rowoff;
      const float s = invsum[row];
      const short4 pv = *(const short4*)&A[(size_t)row * KDIM + tcol0 + coff];
      float4 o;
      o.x = bf16f(pv.x) * s; o.y = bf16f(pv.y) * s;
      o.z = bf16f(pv.z) * s; o.w = bf16f(pv.w) * s;
      *(float4*)&tokens[(size_t)row * V_DIM + tcol0 + coff] = o;
    }
  }
}

// invsum[r] = 1 / sum(partials[r][0..32))
__global__ __launch_bounds__(256) void k_rowsum_inv(const float* __restrict__ partials,
                                                    float* __restrict__ invsum) {
  const int r = blockIdx.x * 256 + threadIdx.x;
  const float4* p = (const float4*)&partials[(size_t)r * 32];
  float s = 0.f;
#pragma unroll
  for (int i = 0; i < 8; ++i) { float4 v = p[i]; s += v.x + v.y + v.z + v.w; }
  invsum[r] = 1.f / s;
}

// =============== FALLBACK PATH (round-1, known-correct) ======================
__global__ __launch_bounds__(256) void k_gemm_nt(const short* __restrict__ A,
                                                 const short* __restrict__ B,
                                                 float* __restrict__ C,
                                                 int lda, int ldb, int ldc, int K) {
  __shared__ __align__(16) short As[128][64];
  __shared__ __align__(16) short Bs[128][64];
  const int t = threadIdx.x;
  const int w = t >> 6, l = t & 63;
  const int lr = l & 15, lh = l >> 4;
  const int m0 = blockIdx.y * 128, n0 = blockIdx.x * 128;
  const int wm = (w >> 1) * 64, wn = (w & 1) * 64;
  floatx4 acc[4][4] = {};
  for (int k0 = 0; k0 < K; k0 += 64) {
    __syncthreads();
#pragma unroll
    for (int i = 0; i < 4; ++i) {
      const int c = i * 256 + t;
      const int r = c >> 3, c8 = (c & 7) * 8;
      *(bf16x8*)&As[r][c8] = *(const bf16x8*)&A[(size_t)(m0 + r) * lda + k0 + c8];
      *(bf16x8*)&Bs[r][c8] = *(const bf16x8*)&B[(size_t)(n0 + r) * ldb + k0 + c8];
    }
    __syncthreads();
#pragma unroll
    for (int kk = 0; kk < 64; kk += 32) {
      bf16x8 af[4], bfr[4];
#pragma unroll
      for (int m = 0; m < 4; ++m) af[m] = *(const bf16x8*)&As[wm + m * 16 + lr][kk + lh * 8];
#pragma unroll
      for (int n = 0; n < 4; ++n) bfr[n] = *(const bf16x8*)&Bs[wn + n * 16 + lr][kk + lh * 8];
#pragma unroll
      for (int m = 0; m < 4; ++m)
#pragma unroll
        for (int n = 0; n < 4; ++n)
          acc[m][n] = __builtin_amdgcn_mfma_f32_16x16x32_bf16(af[m], bfr[n], acc[m][n], 0, 0, 0);
    }
  }
#pragma unroll
  for (int m = 0; m < 4; ++m)
#pragma unroll
    for (int n = 0; n < 4; ++n) {
      const int col = n0 + wn + n * 16 + lr;
#pragma unroll
      for (int j = 0; j < 4; ++j)
        C[(size_t)(m0 + wm + m * 16 + lh * 4 + j) * ldc + col] = acc[m][n][j];
    }
}

__global__ __launch_bounds__(256) void k_gemm_nt_f32a(const float* __restrict__ A,
                                                      const short* __restrict__ B,
                                                      float* __restrict__ C,
                                                      int lda, int ldb, int ldc, int K) {
  __shared__ __align__(16) short As[128][64];
  __shared__ __align__(16) short Bs[128][64];
  const int t = threadIdx.x;
  const int w = t >> 6, l = t & 63;
  const int lr = l & 15, lh = l >> 4;
  const int m0 = blockIdx.y * 128, n0 = blockIdx.x * 128;
  const int wm = (w >> 1) * 64, wn = (w & 1) * 64;
  floatx4 acc[4][4] = {};
  for (int k0 = 0; k0 < K; k0 += 64) {
    __syncthreads();
#pragma unroll
    for (int i = 0; i < 4; ++i) {
      const int c = i * 256 + t;
      const int r = c >> 3, c8 = (c & 7) * 8;
      const float4 a0 = *(const float4*)&A[(size_t)(m0 + r) * lda + k0 + c8];
      const float4 a1 = *(const float4*)&A[(size_t)(m0 + r) * lda + k0 + c8 + 4];
      bf16x8 va;
      va[0] = f2bf(a0.x); va[1] = f2bf(a0.y); va[2] = f2bf(a0.z); va[3] = f2bf(a0.w);
      va[4] = f2bf(a1.x); va[5] = f2bf(a1.y); va[6] = f2bf(a1.z); va[7] = f2bf(a1.w);
      *(bf16x8*)&As[r][c8] = va;
      *(bf16x8*)&Bs[r][c8] = *(const bf16x8*)&B[(size_t)(n0 + r) * ldb + k0 + c8];
    }
    __syncthreads();
#pragma unroll
    for (int kk = 0; kk < 64; kk += 32) {
      bf16x8 af[4], bfr[4];
#pragma unroll
      for (int m = 0; m < 4; ++m) af[m] = *(const bf16x8*)&As[wm + m * 16 + lr][kk + lh * 8];
#pragma unroll
      for (int n = 0; n < 4; ++n) bfr[n] = *(const bf16x8*)&Bs[wn + n * 16 + lr][kk + lh * 8];
#pragma unroll
      for (int m = 0; m < 4; ++m)
#pragma unroll
        for (int n = 0; n < 4; ++n)
          acc[m][n] = __builtin_amdgcn_mfma_f32_16x16x32_bf16(af[m], bfr[n], acc[m][n], 0, 0, 0);
    }
  }
#pragma unroll
  for (int m = 0; m < 4; ++m)
#pragma unroll
    for (int n = 0; n < 4; ++n) {
      const int col = n0 + wn + n * 16 + lr;
#pragma unroll
      for (int j = 0; j < 4; ++j)
        C[(size_t)(m0 + wm + m * 16 + lh * 4 + j) * ldc + col] = acc[m][n][j];
    }
}

__global__ __launch_bounds__(256) void k_gumbel_softmax(float* __restrict__ S,
                                                        const float* __restrict__ U) {
  const int t = threadIdx.x;
  const int w = t >> 6, l = t & 63;
  const size_t base = (size_t)blockIdx.x * V_DIM + t * 8;
  const float4 s0 = *(const float4*)&S[base];
  const float4 s1 = *(const float4*)&S[base + 4];
  const float4 u0 = *(const float4*)&U[base];
  const float4 u1 = *(const float4*)&U[base + 4];
  float x[8];
  x[0] = s0.x - 2.f * __logf(-__logf(u0.x + 1e-10f) + 1e-10f);
  x[1] = s0.y - 2.f * __logf(-__logf(u0.y + 1e-10f) + 1e-10f);
  x[2] = s0.z - 2.f * __logf(-__logf(u0.z + 1e-10f) + 1e-10f);
  x[3] = s0.w - 2.f * __logf(-__logf(u0.w + 1e-10f) + 1e-10f);
  x[4] = s1.x - 2.f * __logf(-__logf(u1.x + 1e-10f) + 1e-10f);
  x[5] = s1.y - 2.f * __logf(-__logf(u1.y + 1e-10f) + 1e-10f);
  x[6] = s1.z - 2.f * __logf(-__logf(u1.z + 1e-10f) + 1e-10f);
  x[7] = s1.w - 2.f * __logf(-__logf(u1.w + 1e-10f) + 1e-10f);
  float lm = x[0];
#pragma unroll
  for (int i = 1; i < 8; ++i) lm = fmaxf(lm, x[i]);
  lm = wave_max(lm);
  __shared__ float redA[4], redB[4];
  if (l == 0) redA[w] = lm;
  __syncthreads();
  const float m = fmaxf(fmaxf(redA[0], redA[1]), fmaxf(redA[2], redA[3]));
  float p[8];
  float ls = 0.f;
#pragma unroll
  for (int i = 0; i < 8; ++i) { p[i] = __expf(x[i] - m); ls += p[i]; }
  ls = wave_sum(ls);
  if (l == 0) redB[w] = ls;
  __syncthreads();
  const float inv = 1.0f / (redB[0] + redB[1] + redB[2] + redB[3]);
  float4 o0 = make_float4(p[0] * inv, p[1] * inv, p[2] * inv, p[3] * inv);
  float4 o1 = make_float4(p[4] * inv, p[5] * inv, p[6] * inv, p[7] * inv);
  *(float4*)&S[base] = o0;
  *(float4*)&S[base + 4] = o1;
}

extern "C" void kernel_launch(void* const* d_in, const int* in_sizes, int n_in,
                              void* d_out, int out_size, void* d_ws, size_t ws_size,
                              hipStream_t stream) {
  const float* z = (const float*)d_in[0];
  const float* W = (const float*)d_in[1];
  const float* U = (const float*)d_in[2];
  float* tokens = (float*)d_out;                    // [N, V] f32
  float* zq = tokens + (size_t)N_ROWS * V_DIM;      // [N, E] f32
  short* zn = (short*)zq;                           // bf16 zn in z_q region

  short* embn = (short*)d_ws;                       // 4 MB
  short* embnT = embn + (size_t)V_DIM * E_DIM;      // 4 MB

  const size_t NEED = (size_t)V_DIM * E_DIM * 2 * 2     // embn + embnT
                    + (size_t)N_ROWS * 32 * 4           // partials (8 MB)
                    + (size_t)N_ROWS * 4                // invsum
                    + (size_t)N_ROWS * V_DIM * 2;       // P~ bf16 (256 MB)

  k_norm_emb<<<V_DIM, 256, 0, stream>>>(W, embn, embnT);
  k_norm_z<<<N_ROWS / 4, 256, 0, stream>>>(z, zn);

  if (ws_size >= NEED) {
    float* partials = (float*)(embnT + (size_t)V_DIM * E_DIM);
    float* invsum = partials + (size_t)N_ROWS * 32;
    short* Pb = (short*)(invsum + N_ROWS);
    // GEMM1 fused gumbel-exp: grid = (65536/256) * (2048/256) = 2048
    k_gemm8<E_DIM, 8, 0><<<2048, 512, 0, stream>>>(
        zn, embn, U, Pb, partials, nullptr, nullptr, nullptr, 2048 / 8);
    k_rowsum_inv<<<N_ROWS / 256, 256, 0, stream>>>(partials, invsum);
    // GEMM2 scaled + fused tokens tail: grid = (65536/256) * (1024/256) = 1024
    k_gemm8<V_DIM, 4, 1><<<1024, 512, 0, stream>>>(
        Pb, embnT, nullptr, nullptr, nullptr, invsum, zq, tokens, 1024 / 8);
  } else {
    k_gemm_nt<<<dim3(V_DIM / 128, N_ROWS / 128), 256, 0, stream>>>(
        zn, embn, tokens, E_DIM, E_DIM, V_DIM, E_DIM);
    k_gumbel_softmax<<<N_ROWS, 256, 0, stream>>>(tokens, U);
    k_gemm_nt_f32a<<<dim3(E_DIM / 128, N_ROWS / 128), 256, 0, stream>>>(
        tokens, embnT, zq, V_DIM, V_DIM, E_DIM, V_DIM);
  }
}

// Round 11
// 1033.309 us; speedup vs baseline: 1.3792x; 1.0058x over previous
//
#include <hip/hip_runtime.h>
#include <hip/hip_bf16.h>
#include <stdint.h>

typedef short bf16x8 __attribute__((ext_vector_type(8)));
typedef float floatx4 __attribute__((ext_vector_type(4)));

#define N_ROWS 65536
#define V_DIM 2048
#define E_DIM 1024

__device__ __forceinline__ short f2bf(float x) {
  union { float f; uint32_t u; } c; c.f = x;
  uint32_t r = (c.u + 0x7FFFu + ((c.u >> 16) & 1u)) >> 16;
  return (short)(uint16_t)r;
}
__device__ __forceinline__ float bf16f(short b) {
  union { uint32_t u; float f; } c; c.u = ((uint32_t)(uint16_t)b) << 16;
  return c.f;
}

__device__ __forceinline__ float wave_sum(float v) {
#pragma unroll
  for (int o = 32; o > 0; o >>= 1) v += __shfl_xor(v, o);
  return v;
}
__device__ __forceinline__ float wave_max(float v) {
#pragma unroll
  for (int o = 32; o > 0; o >>= 1) v = fmaxf(v, __shfl_xor(v, o));
  return v;
}

__device__ __forceinline__ void gll16(const short* g, short* l) {
  __builtin_amdgcn_global_load_lds(
      (const __attribute__((address_space(1))) void*)g,
      (__attribute__((address_space(3))) void*)l, 16, 0, 0);
}

// fallback 128B-row swizzled fragment read
#define FRAG(base, R, c) \
  (*(const bf16x8*)((const char*)(base) + ((R) << 7) + (((((c) >> 3) ^ ((R) & 7))) << 4)))

// ---------------- normalize emb rows -> bf16 embn [V][E] and embnT [E][V] ----
__global__ __launch_bounds__(256) void k_norm_emb(const float* __restrict__ W,
                                                  short* __restrict__ embn,
                                                  short* __restrict__ embnT) {
  const int v = blockIdx.x;
  const int t = threadIdx.x;
  const int w = t >> 6, l = t & 63;
  const float4 val = *(const float4*)&W[(size_t)v * E_DIM + t * 4];
  float ss = val.x * val.x + val.y * val.y + val.z * val.z + val.w * val.w;
  ss = wave_sum(ss);
  __shared__ float red[4];
  if (l == 0) red[w] = ss;
  __syncthreads();
  ss = red[0] + red[1] + red[2] + red[3];
  const float inv = 1.0f / fmaxf(sqrtf(ss), 1e-12f);
  short4 o;
  o.x = f2bf(val.x * inv);
  o.y = f2bf(val.y * inv);
  o.z = f2bf(val.z * inv);
  o.w = f2bf(val.w * inv);
  *(short4*)&embn[(size_t)v * E_DIM + t * 4] = o;
  embnT[(size_t)(t * 4 + 0) * V_DIM + v] = o.x;
  embnT[(size_t)(t * 4 + 1) * V_DIM + v] = o.y;
  embnT[(size_t)(t * 4 + 2) * V_DIM + v] = o.z;
  embnT[(size_t)(t * 4 + 3) * V_DIM + v] = o.w;
}

// ---------------- normalize z rows, fold in kappa_q/T, -> bf16 zn [N][E] -----
__global__ __launch_bounds__(256) void k_norm_z(const float* __restrict__ Z,
                                                short* __restrict__ zn) {
  const int w = threadIdx.x >> 6, l = threadIdx.x & 63;
  const int row = blockIdx.x * 4 + w;
  const float* zr = Z + (size_t)row * E_DIM;
  float4 v[4];
  float ss = 0.f;
#pragma unroll
  for (int i = 0; i < 4; ++i) {
    v[i] = *(const float4*)&zr[(i * 64 + l) * 4];
    ss += v[i].x * v[i].x + v[i].y * v[i].y + v[i].z * v[i].z + v[i].w * v[i].w;
  }
  ss = wave_sum(ss);
  const float SCALE = 2.0f * (expf(-2.995732273553991f) + 1.0f);  // kappa_q / T
  const float inv = SCALE / fmaxf(sqrtf(ss), 1e-12f);
  short* zo = zn + (size_t)row * E_DIM;
#pragma unroll
  for (int i = 0; i < 4; ++i) {
    short4 o;
    o.x = f2bf(v[i].x * inv);
    o.y = f2bf(v[i].y * inv);
    o.z = f2bf(v[i].z * inv);
    o.w = f2bf(v[i].w * inv);
    *(short4*)&zo[(i * 64 + l) * 4] = o;
  }
}

// =============== FAST PATH: 256x256 tile, BK=32, 4-buffer ring, counted vmcnt,
// two fine phases per K-tile (R4 form, measured best).
// EPI 0: gumbel-exp (direct U reads, R5 form) -> Pb bf16 + partials.
// EPI 1: col-major block order (embnT L2-residency); invsum-scaled -> C; then
//        tokens tail: re-read own L2-hot Pb quarter, write f32 tokens slice.
template <int KDIM, int NBX, int EPI>
__global__ __launch_bounds__(512, 2) void k_gemm8(
    const short* __restrict__ A, const short* __restrict__ B,
    const float* __restrict__ U, short* __restrict__ Pb,
    float* __restrict__ partials, const float* __restrict__ invsum,
    float* __restrict__ C, float* __restrict__ tokens, int cpx) {
  __shared__ __align__(16) short Sm[65536];  // A ring: 4 x 16KB at byte 0; B ring at byte 65536
  const int NT = KDIM / 32;
  const int tid = threadIdx.x;
  const int wv = tid >> 6, lane = tid & 63;
  const int lr = lane & 15, lh = lane >> 4;
  const int wr = wv >> 2, wc = wv & 3;  // 2x4 wave grid
  // XCD-chunked bijective swizzle (grid multiple of 8)
  const int d = blockIdx.x;
  const int L = (d & 7) * cpx + (d >> 3);
  // EPI0: row-major (zn panel shared by consecutive L).  EPI1: col-major
  // (one embnT panel per XCD stays L2-resident while Pb streams).
  const int by = (EPI == 0) ? (L / NBX) : (L & 255);
  const int bx = (EPI == 0) ? (L % NBX) : (L >> 8);
  const int m0 = by * 256, n0 = bx * 256;
  // staging: LDS row R_w = q*128 + wv*16 + (lane>>2); linear dest; source granule
  // pre-swizzled: kg = (lane&3) ^ f(R_w), f(R) = (R ^ (R>>2)) & 3
  const int sg = (((lane & 3) ^ ((lane >> 2) & 3) ^ ((lane >> 4) & 3)) << 3);
  const int srow = wv * 16 + (lane >> 2);
  const short* gA = A + (size_t)(m0 + srow) * KDIM + sg;
  const short* gB = B + (size_t)(n0 + srow) * KDIM + sg;
  // fragment read: slot = lh ^ f(R); f(R) = (lr ^ (lr>>2)) & 3 for all frag rows
  const int fslot = lh ^ ((lr ^ (lr >> 2)) & 3);
  const int aoff = wr * 8192 + lr * 64 + fslot * 16;  // bytes within A buffer
  const int boff = wc * 4096 + lr * 64 + fslot * 16;  // bytes within B buffer

  // prologue: stage tiles 0 and 1
#pragma unroll
  for (int t = 0; t < 2; ++t) {
#pragma unroll
    for (int q = 0; q < 2; ++q) {
      gll16(gA + (size_t)(q * 128) * KDIM + t * 32, Sm + t * 8192 + q * 4096 + wv * 512);
      gll16(gB + (size_t)(q * 128) * KDIM + t * 32, Sm + 32768 + t * 8192 + q * 4096 + wv * 512);
    }
  }
  asm volatile("s_waitcnt vmcnt(4)" ::: "memory");
  __builtin_amdgcn_s_barrier();
  __builtin_amdgcn_sched_barrier(0);

  floatx4 acc[8][4] = {};

#define DO_TILE(KT, STAGE, VMN)                                                     \
  {                                                                                 \
    const int cb_ = (KT) & 3;                                                       \
    const char* Ab_ = (const char*)Sm + cb_ * 16384;                                \
    const char* Bb_ = (const char*)Sm + 65536 + cb_ * 16384;                        \
    short* An_ = Sm + (((KT) + 2) & 3) * 8192;                                      \
    short* Bn_ = Sm + 32768 + (((KT) + 2) & 3) * 8192;                              \
    const size_t kc_ = (size_t)((KT) + 2) * 32;                                     \
    bf16x8 bfr[4], af[4];                                                           \
    /* ---------- phase A: B-frags + A-frags(m0..3) | stage A halves ---------- */ \
    _Pragma("unroll")                                                               \
    for (int n = 0; n < 4; ++n) bfr[n] = *(const bf16x8*)(Bb_ + boff + n * 1024);   \
    _Pragma("unroll")                                                               \
    for (int i = 0; i < 4; ++i) af[i] = *(const bf16x8*)(Ab_ + aoff + i * 1024);    \
    if (STAGE) {                                                                    \
      gll16(gA + kc_, An_ + wv * 512);                                              \
      gll16(gA + (size_t)128 * KDIM + kc_, An_ + 4096 + wv * 512);                  \
    }                                                                               \
    __builtin_amdgcn_s_barrier();                                                   \
    asm volatile("s_waitcnt lgkmcnt(0)" ::: "memory");                              \
    __builtin_amdgcn_sched_barrier(0);                                              \
    __builtin_amdgcn_s_setprio(1);                                                  \
    _Pragma("unroll")                                                               \
    for (int i = 0; i < 4; ++i) {                                                   \
      _Pragma("unroll")                                                             \
      for (int n = 0; n < 4; ++n)                                                   \
        acc[i][n] =                                                                 \
            __builtin_amdgcn_mfma_f32_16x16x32_bf16(af[i], bfr[n], acc[i][n], 0, 0, 0); \
    }                                                                               \
    __builtin_amdgcn_s_setprio(0);                                                  \
    __builtin_amdgcn_s_barrier();                                                   \
    /* ---------- phase B: A-frags(m4..7) | stage B halves -------------------- */ \
    _Pragma("unroll")                                                               \
    for (int i = 0; i < 4; ++i)                                                     \
      af[i] = *(const bf16x8*)(Ab_ + aoff + 4096 + i * 1024);                       \
    if (STAGE) {                                                                    \
      gll16(gB + kc_, Bn_ + wv * 512);                                              \
      gll16(gB + (size_t)128 * KDIM + kc_, Bn_ + 4096 + wv * 512);                  \
    }                                                                               \
    __builtin_amdgcn_s_barrier();                                                   \
    asm volatile("s_waitcnt lgkmcnt(0)" ::: "memory");                              \
    __builtin_amdgcn_sched_barrier(0);                                              \
    __builtin_amdgcn_s_setprio(1);                                                  \
    _Pragma("unroll")                                                               \
    for (int i = 0; i < 4; ++i) {                                                   \
      _Pragma("unroll")                                                             \
      for (int n = 0; n < 4; ++n)                                                   \
        acc[4 + i][n] =                                                             \
            __builtin_amdgcn_mfma_f32_16x16x32_bf16(af[i], bfr[n], acc[4 + i][n], 0, 0, 0); \
    }                                                                               \
    __builtin_amdgcn_s_setprio(0);                                                  \
    asm volatile("s_waitcnt vmcnt(" #VMN ")" ::: "memory");                         \
    __builtin_amdgcn_s_barrier();                                                   \
    __builtin_amdgcn_sched_barrier(0);                                              \
  }

  for (int kt = 0; kt < NT - 2; ++kt) DO_TILE(kt, 1, 4);
  DO_TILE(NT - 2, 0, 0);
  DO_TILE(NT - 1, 0, 0);
#undef DO_TILE

  const int gr0 = m0 + wr * 128 + lh * 4;
  const int gc0 = n0 + wc * 64 + lr;
  if (EPI == 0) {
    // R5-form epilogue: direct U reads inline (compiler schedules the loads)
    float rs[8][4] = {};
#pragma unroll
    for (int m = 0; m < 8; ++m)
#pragma unroll
      for (int n = 0; n < 4; ++n) {
        const int col = gc0 + n * 16;
#pragma unroll
        for (int j = 0; j < 4; ++j) {
          const int row = gr0 + m * 16 + j;
          const size_t idx = (size_t)row * V_DIM + col;
          const float u = U[idx];
          const float e = __expf(acc[m][n][j] - 2.f * __logf(-__logf(u + 1e-10f) + 1e-10f));
          const short eb = f2bf(e);
          Pb[idx] = eb;
          rs[m][j] += bf16f(eb);
        }
      }
#pragma unroll
    for (int m = 0; m < 8; ++m)
#pragma unroll
      for (int j = 0; j < 4; ++j) {
        float s = rs[m][j];
        s += __shfl_xor(s, 1); s += __shfl_xor(s, 2);
        s += __shfl_xor(s, 4); s += __shfl_xor(s, 8);
        if (lr == 0)
          partials[(size_t)(gr0 + m * 16 + j) * 32 + bx * 4 + wc] = s;
      }
  } else {
#pragma unroll
    for (int m = 0; m < 8; ++m)
#pragma unroll
      for (int j = 0; j < 4; ++j) {
        const int row = gr0 + m * 16 + j;
        const float s = invsum[row];
#pragma unroll
        for (int n = 0; n < 4; ++n)
          C[(size_t)row * E_DIM + gc0 + n * 16] = acc[m][n][j] * s;
      }
    // ---- tokens tail: rows m0..m0+255, cols bx*512..bx*512+511 ----
    // Pb slice is L2-hot (this block staged exactly these rows in the mainloop).
    const int tcol0 = bx * 512;
    const int rowoff = tid >> 7;        // 0..3
    const int coff = (tid & 127) * 4;   // 0..508
    for (int it = 0; it < 64; ++it) {
      const int row = m0 + it * 4 + rowoff;
      const float s = invsum[row];
      const short4 pv = *(const short4*)&A[(size_t)row * KDIM + tcol0 + coff];
      float4 o;
      o.x = bf16f(pv.x) * s; o.y = bf16f(pv.y) * s;
      o.z = bf16f(pv.z) * s; o.w = bf16f(pv.w) * s;
      *(float4*)&tokens[(size_t)row * V_DIM + tcol0 + coff] = o;
    }
  }
}

// invsum[r] = 1 / sum(partials[r][0..32))
__global__ __launch_bounds__(256) void k_rowsum_inv(const float* __restrict__ partials,
                                                    float* __restrict__ invsum) {
  const int r = blockIdx.x * 256 + threadIdx.x;
  const float4* p = (const float4*)&partials[(size_t)r * 32];
  float s = 0.f;
#pragma unroll
  for (int i = 0; i < 8; ++i) { float4 v = p[i]; s += v.x + v.y + v.z + v.w; }
  invsum[r] = 1.f / s;
}

// =============== FALLBACK PATH (round-1, known-correct) ======================
__global__ __launch_bounds__(256) void k_gemm_nt(const short* __restrict__ A,
                                                 const short* __restrict__ B,
                                                 float* __restrict__ C,
                                                 int lda, int ldb, int ldc, int K) {
  __shared__ __align__(16) short As[128][64];
  __shared__ __align__(16) short Bs[128][64];
  const int t = threadIdx.x;
  const int w = t >> 6, l = t & 63;
  const int lr = l & 15, lh = l >> 4;
  const int m0 = blockIdx.y * 128, n0 = blockIdx.x * 128;
  const int wm = (w >> 1) * 64, wn = (w & 1) * 64;
  floatx4 acc[4][4] = {};
  for (int k0 = 0; k0 < K; k0 += 64) {
    __syncthreads();
#pragma unroll
    for (int i = 0; i < 4; ++i) {
      const int c = i * 256 + t;
      const int r = c >> 3, c8 = (c & 7) * 8;
      *(bf16x8*)&As[r][c8] = *(const bf16x8*)&A[(size_t)(m0 + r) * lda + k0 + c8];
      *(bf16x8*)&Bs[r][c8] = *(const bf16x8*)&B[(size_t)(n0 + r) * ldb + k0 + c8];
    }
    __syncthreads();
#pragma unroll
    for (int kk = 0; kk < 64; kk += 32) {
      bf16x8 af[4], bfr[4];
#pragma unroll
      for (int m = 0; m < 4; ++m) af[m] = *(const bf16x8*)&As[wm + m * 16 + lr][kk + lh * 8];
#pragma unroll
      for (int n = 0; n < 4; ++n) bfr[n] = *(const bf16x8*)&Bs[wn + n * 16 + lr][kk + lh * 8];
#pragma unroll
      for (int m = 0; m < 4; ++m)
#pragma unroll
        for (int n = 0; n < 4; ++n)
          acc[m][n] = __builtin_amdgcn_mfma_f32_16x16x32_bf16(af[m], bfr[n], acc[m][n], 0, 0, 0);
    }
  }
#pragma unroll
  for (int m = 0; m < 4; ++m)
#pragma unroll
    for (int n = 0; n < 4; ++n) {
      const int col = n0 + wn + n * 16 + lr;
#pragma unroll
      for (int j = 0; j < 4; ++j)
        C[(size_t)(m0 + wm + m * 16 + lh * 4 + j) * ldc + col] = acc[m][n][j];
    }
}

__global__ __launch_bounds__(256) void k_gemm_nt_f32a(const float* __restrict__ A,
                                                      const short* __restrict__ B,
                                                      float* __restrict__ C,
                                                      int lda, int ldb, int ldc, int K) {
  __shared__ __align__(16) short As[128][64];
  __shared__ __align__(16) short Bs[128][64];
  const int t = threadIdx.x;
  const int w = t >> 6, l = t & 63;
  const int lr = l & 15, lh = l >> 4;
  const int m0 = blockIdx.y * 128, n0 = blockIdx.x * 128;
  const int wm = (w >> 1) * 64, wn = (w & 1) * 64;
  floatx4 acc[4][4] = {};
  for (int k0 = 0; k0 < K; k0 += 64) {
    __syncthreads();
#pragma unroll
    for (int i = 0; i < 4; ++i) {
      const int c = i * 256 + t;
      const int r = c >> 3, c8 = (c & 7) * 8;
      const float4 a0 = *(const float4*)&A[(size_t)(m0 + r) * lda + k0 + c8];
      const float4 a1 = *(const float4*)&A[(size_t)(m0 + r) * lda + k0 + c8 + 4];
      bf16x8 va;
      va[0] = f2bf(a0.x); va[1] = f2bf(a0.y); va[2] = f2bf(a0.z); va[3] = f2bf(a0.w);
      va[4] = f2bf(a1.x); va[5] = f2bf(a1.y); va[6] = f2bf(a1.z); va[7] = f2bf(a1.w);
      *(bf16x8*)&As[r][c8] = va;
      *(bf16x8*)&Bs[r][c8] = *(const bf16x8*)&B[(size_t)(n0 + r) * ldb + k0 + c8];
    }
    __syncthreads();
#pragma unroll
    for (int kk = 0; kk < 64; kk += 32) {
      bf16x8 af[4], bfr[4];
#pragma unroll
      for (int m = 0; m < 4; ++m) af[m] = *(const bf16x8*)&As[wm + m * 16 + lr][kk + lh * 8];
#pragma unroll
      for (int n = 0; n < 4; ++n) bfr[n] = *(const bf16x8*)&Bs[wn + n * 16 + lr][kk + lh * 8];
#pragma unroll
      for (int m = 0; m < 4; ++m)
#pragma unroll
        for (int n = 0; n < 4; ++n)
          acc[m][n] = __builtin_amdgcn_mfma_f32_16x16x32_bf16(af[m], bfr[n], acc[m][n], 0, 0, 0);
    }
  }
#pragma unroll
  for (int m = 0; m < 4; ++m)
#pragma unroll
    for (int n = 0; n < 4; ++n) {
      const int col = n0 + wn + n * 16 + lr;
#pragma unroll
      for (int j = 0; j < 4; ++j)
        C[(size_t)(m0 + wm + m * 16 + lh * 4 + j) * ldc + col] = acc[m][n][j];
    }
}

__global__ __launch_bounds__(256) void k_gumbel_softmax(float* __restrict__ S,
                                                        const float* __restrict__ U) {
  const int t = threadIdx.x;
  const int w = t >> 6, l = t & 63;
  const size_t base = (size_t)blockIdx.x * V_DIM + t * 8;
  const float4 s0 = *(const float4*)&S[base];
  const float4 s1 = *(const float4*)&S[base + 4];
  const float4 u0 = *(const float4*)&U[base];
  const float4 u1 = *(const float4*)&U[base + 4];
  float x[8];
  x[0] = s0.x - 2.f * __logf(-__logf(u0.x + 1e-10f) + 1e-10f);
  x[1] = s0.y - 2.f * __logf(-__logf(u0.y + 1e-10f) + 1e-10f);
  x[2] = s0.z - 2.f * __logf(-__logf(u0.z + 1e-10f) + 1e-10f);
  x[3] = s0.w - 2.f * __logf(-__logf(u0.w + 1e-10f) + 1e-10f);
  x[4] = s1.x - 2.f * __logf(-__logf(u1.x + 1e-10f) + 1e-10f);
  x[5] = s1.y - 2.f * __logf(-__logf(u1.y + 1e-10f) + 1e-10f);
  x[6] = s1.z - 2.f * __logf(-__logf(u1.z + 1e-10f) + 1e-10f);
  x[7] = s1.w - 2.f * __logf(-__logf(u1.w + 1e-10f) + 1e-10f);
  float lm = x[0];
#pragma unroll
  for (int i = 1; i < 8; ++i) lm = fmaxf(lm, x[i]);
  lm = wave_max(lm);
  __shared__ float redA[4], redB[4];
  if (l == 0) redA[w] = lm;
  __syncthreads();
  const float m = fmaxf(fmaxf(redA[0], redA[1]), fmaxf(redA[2], redA[3]));
  float p[8];
  float ls = 0.f;
#pragma unroll
  for (int i = 0; i < 8; ++i) { p[i] = __expf(x[i] - m); ls += p[i]; }
  ls = wave_sum(ls);
  if (l == 0) redB[w] = ls;
  __syncthreads();
  const float inv = 1.0f / (redB[0] + redB[1] + redB[2] + redB[3]);
  float4 o0 = make_float4(p[0] * inv, p[1] * inv, p[2] * inv, p[3] * inv);
  float4 o1 = make_float4(p[4] * inv, p[5] * inv, p[6] * inv, p[7] * inv);
  *(float4*)&S[base] = o0;
  *(float4*)&S[base + 4] = o1;
}

extern "C" void kernel_launch(void* const* d_in, const int* in_sizes, int n_in,
                              void* d_out, int out_size, void* d_ws, size_t ws_size,
                              hipStream_t stream) {
  const float* z = (const float*)d_in[0];
  const float* W = (const float*)d_in[1];
  const float* U = (const float*)d_in[2];
  float* tokens = (float*)d_out;                    // [N, V] f32
  float* zq = tokens + (size_t)N_ROWS * V_DIM;      // [N, E] f32
  short* zn = (short*)zq;                           // bf16 zn in z_q region

  short* embn = (short*)d_ws;                       // 4 MB
  short* embnT = embn + (size_t)V_DIM * E_DIM;      // 4 MB

  const size_t NEED = (size_t)V_DIM * E_DIM * 2 * 2     // embn + embnT
                    + (size_t)N_ROWS * 32 * 4           // partials (8 MB)
                    + (size_t)N_ROWS * 4                // invsum
                    + (size_t)N_ROWS * V_DIM * 2;       // P~ bf16 (256 MB)

  k_norm_emb<<<V_DIM, 256, 0, stream>>>(W, embn, embnT);
  k_norm_z<<<N_ROWS / 4, 256, 0, stream>>>(z, zn);

  if (ws_size >= NEED) {
    float* partials = (float*)(embnT + (size_t)V_DIM * E_DIM);
    float* invsum = partials + (size_t)N_ROWS * 32;
    short* Pb = (short*)(invsum + N_ROWS);
    // GEMM1 fused gumbel-exp: grid = (65536/256) * (2048/256) = 2048
    k_gemm8<E_DIM, 8, 0><<<2048, 512, 0, stream>>>(
        zn, embn, U, Pb, partials, nullptr, nullptr, nullptr, 2048 / 8);
    k_rowsum_inv<<<N_ROWS / 256, 256, 0, stream>>>(partials, invsum);
    // GEMM2 scaled + fused tokens tail: grid = (65536/256) * (1024/256) = 1024
    k_gemm8<V_DIM, 4, 1><<<1024, 512, 0, stream>>>(
        Pb, embnT, nullptr, nullptr, nullptr, invsum, zq, tokens, 1024 / 8);
  } else {
    k_gemm_nt<<<dim3(V_DIM / 128, N_ROWS / 128), 256, 0, stream>>>(
        zn, embn, tokens, E_DIM, E_DIM, V_DIM, E_DIM);
    k_gumbel_softmax<<<N_ROWS, 256, 0, stream>>>(tokens, U);
    k_gemm_nt_f32a<<<dim3(E_DIM / 128, N_ROWS / 128), 256, 0, stream>>>(
        tokens, embnT, zq, V_DIM, V_DIM, E_DIM, V_DIM);
  }
}

// Round 12
// 925.956 us; speedup vs baseline: 1.5392x; 1.1159x over previous
//
#include <hip/hip_runtime.h>
#include <hip/hip_bf16.h>
#include <stdint.h>

typedef short bf16x8 __attribute__((ext_vector_type(8)));
typedef float floatx4 __attribute__((ext_vector_type(4)));

#define N_ROWS 65536
#define V_DIM 2048
#define E_DIM 1024

__device__ __forceinline__ short f2bf(float x) {
  union { float f; uint32_t u; } c; c.f = x;
  uint32_t r = (c.u + 0x7FFFu + ((c.u >> 16) & 1u)) >> 16;
  return (short)(uint16_t)r;
}
__device__ __forceinline__ float bf16f(short b) {
  union { uint32_t u; float f; } c; c.u = ((uint32_t)(uint16_t)b) << 16;
  return c.f;
}

__device__ __forceinline__ float wave_sum(float v) {
#pragma unroll
  for (int o = 32; o > 0; o >>= 1) v += __shfl_xor(v, o);
  return v;
}
__device__ __forceinline__ float wave_max(float v) {
#pragma unroll
  for (int o = 32; o > 0; o >>= 1) v = fmaxf(v, __shfl_xor(v, o));
  return v;
}

__device__ __forceinline__ void gll16(const short* g, short* l) {
  __builtin_amdgcn_global_load_lds(
      (const __attribute__((address_space(1))) void*)g,
      (__attribute__((address_space(3))) void*)l, 16, 0, 0);
}

// ---------------- normalize emb rows -> bf16 embn [V][E] and embnT [E][V] ----
__global__ __launch_bounds__(256) void k_norm_emb(const float* __restrict__ W,
                                                  short* __restrict__ embn,
                                                  short* __restrict__ embnT) {
  const int v = blockIdx.x;
  const int t = threadIdx.x;
  const int w = t >> 6, l = t & 63;
  const float4 val = *(const float4*)&W[(size_t)v * E_DIM + t * 4];
  float ss = val.x * val.x + val.y * val.y + val.z * val.z + val.w * val.w;
  ss = wave_sum(ss);
  __shared__ float red[4];
  if (l == 0) red[w] = ss;
  __syncthreads();
  ss = red[0] + red[1] + red[2] + red[3];
  const float inv = 1.0f / fmaxf(sqrtf(ss), 1e-12f);
  short4 o;
  o.x = f2bf(val.x * inv);
  o.y = f2bf(val.y * inv);
  o.z = f2bf(val.z * inv);
  o.w = f2bf(val.w * inv);
  *(short4*)&embn[(size_t)v * E_DIM + t * 4] = o;
  embnT[(size_t)(t * 4 + 0) * V_DIM + v] = o.x;
  embnT[(size_t)(t * 4 + 1) * V_DIM + v] = o.y;
  embnT[(size_t)(t * 4 + 2) * V_DIM + v] = o.z;
  embnT[(size_t)(t * 4 + 3) * V_DIM + v] = o.w;
}

// ---------------- normalize z rows, fold in kappa_q/T, -> bf16 zn [N][E] -----
__global__ __launch_bounds__(256) void k_norm_z(const float* __restrict__ Z,
                                                short* __restrict__ zn) {
  const int w = threadIdx.x >> 6, l = threadIdx.x & 63;
  const int row = blockIdx.x * 4 + w;
  const float* zr = Z + (size_t)row * E_DIM;
  float4 v[4];
  float ss = 0.f;
#pragma unroll
  for (int i = 0; i < 4; ++i) {
    v[i] = *(const float4*)&zr[(i * 64 + l) * 4];
    ss += v[i].x * v[i].x + v[i].y * v[i].y + v[i].z * v[i].z + v[i].w * v[i].w;
  }
  ss = wave_sum(ss);
  const float SCALE = 2.0f * (expf(-2.995732273553991f) + 1.0f);  // kappa_q / T
  const float inv = SCALE / fmaxf(sqrtf(ss), 1e-12f);
  short* zo = zn + (size_t)row * E_DIM;
#pragma unroll
  for (int i = 0; i < 4; ++i) {
    short4 o;
    o.x = f2bf(v[i].x * inv);
    o.y = f2bf(v[i].y * inv);
    o.z = f2bf(v[i].z * inv);
    o.w = f2bf(v[i].w * inv);
    *(short4*)&zo[(i * 64 + l) * 4] = o;
  }
}

// =============== FAST PATH: 256x256 tile, BK=32, 4-buffer ring, counted vmcnt,
// two fine phases per K-tile.
// EPI 0: gumbel-exp (direct U reads) -> Pb bf16 + partials.
// EPI 1: invsum-scaled -> C; tokens STREAMED inside the mainloop (TOKW): on
//        tiles kt>>4==bx each thread reads back its own staged LDS A (== Pb
//        bits), scales by preloaded invsum, stores f32 tokens. Stores are
//        always YOUNGER than the loads the counted waits target:
//        queue = [ld(kt+1)4][st(kt-1)4][ld(kt+2)4][st(kt)4] -> vmcnt(12) in
//        the TOKW run, 8 at its boundaries, 4 elsewhere. Never drains stores
//        in the steady state (the R8 failure mode, fixed).
template <int KDIM, int NBX, int EPI>
__global__ __launch_bounds__(512, 2) void k_gemm8(
    const short* __restrict__ A, const short* __restrict__ B,
    const float* __restrict__ U, short* __restrict__ Pb,
    float* __restrict__ partials, const float* __restrict__ invsum,
    float* __restrict__ C, float* __restrict__ tokens, int cpx) {
  __shared__ __align__(16) short Sm[65536];  // A ring: 4 x 16KB at byte 0; B ring at byte 65536
  const int NT = KDIM / 32;
  const int tid = threadIdx.x;
  const int wv = tid >> 6, lane = tid & 63;
  const int lr = lane & 15, lh = lane >> 4;
  const int wr = wv >> 2, wc = wv & 3;  // 2x4 wave grid
  // XCD-chunked bijective swizzle (grid multiple of 8); row-major block order
  // (consecutive L share the A row-panel -> L2 hits on A staging).
  const int d = blockIdx.x;
  const int L = (d & 7) * cpx + (d >> 3);
  const int by = L / NBX, bx = L % NBX;
  const int m0 = by * 256, n0 = bx * 256;
  // staging: LDS row R_w = q*128 + wv*16 + (lane>>2); linear dest; source granule
  // pre-swizzled: kg = (lane&3) ^ f(R_w), f(R) = (R ^ (R>>2)) & 3
  const int sg = (((lane & 3) ^ ((lane >> 2) & 3) ^ ((lane >> 4) & 3)) << 3);
  const int srow = wv * 16 + (lane >> 2);
  const short* gA = A + (size_t)(m0 + srow) * KDIM + sg;
  const short* gB = B + (size_t)(n0 + srow) * KDIM + sg;
  // fragment read: slot = lh ^ f(R); f(R) = (lr ^ (lr>>2)) & 3 for all frag rows
  const int fslot = lh ^ ((lr ^ (lr >> 2)) & 3);
  const int aoff = wr * 8192 + lr * 64 + fslot * 16;  // bytes within A buffer
  const int boff = wc * 4096 + lr * 64 + fslot * 16;  // bytes within B buffer

  // EPI1: invsum for this thread's staged rows (tokens scale); loaded before
  // the prologue so they retire long before first use.
  float inv0 = 0.f, inv1 = 0.f;
  if (EPI == 1) {
    inv0 = invsum[m0 + srow];
    inv1 = invsum[m0 + 128 + srow];
  }

  // prologue: stage tiles 0 and 1
#pragma unroll
  for (int t = 0; t < 2; ++t) {
#pragma unroll
    for (int q = 0; q < 2; ++q) {
      gll16(gA + (size_t)(q * 128) * KDIM + t * 32, Sm + t * 8192 + q * 4096 + wv * 512);
      gll16(gB + (size_t)(q * 128) * KDIM + t * 32, Sm + 32768 + t * 8192 + q * 4096 + wv * 512);
    }
  }
  asm volatile("s_waitcnt vmcnt(4)" ::: "memory");
  __builtin_amdgcn_s_barrier();
  __builtin_amdgcn_sched_barrier(0);

  floatx4 acc[8][4] = {};

#define DO_TILE(KT, STAGE, VMN, TOKW_)                                              \
  {                                                                                 \
    const int cb_ = (KT) & 3;                                                       \
    const char* Ab_ = (const char*)Sm + cb_ * 16384;                                \
    const char* Bb_ = (const char*)Sm + 65536 + cb_ * 16384;                        \
    short* An_ = Sm + (((KT) + 2) & 3) * 8192;                                      \
    short* Bn_ = Sm + 32768 + (((KT) + 2) & 3) * 8192;                              \
    const size_t kc_ = (size_t)((KT) + 2) * 32;                                     \
    bf16x8 bfr[4], af[4];                                                           \
    /* ---------- phase A: B-frags + A-frags(m0..3) | stage A halves ---------- */ \
    _Pragma("unroll")                                                               \
    for (int n = 0; n < 4; ++n) bfr[n] = *(const bf16x8*)(Bb_ + boff + n * 1024);   \
    _Pragma("unroll")                                                               \
    for (int i = 0; i < 4; ++i) af[i] = *(const bf16x8*)(Ab_ + aoff + i * 1024);    \
    if (STAGE) {                                                                    \
      gll16(gA + kc_, An_ + wv * 512);                                              \
      gll16(gA + (size_t)128 * KDIM + kc_, An_ + 4096 + wv * 512);                  \
    }                                                                               \
    __builtin_amdgcn_s_barrier();                                                   \
    asm volatile("s_waitcnt lgkmcnt(0)" ::: "memory");                              \
    __builtin_amdgcn_sched_barrier(0);                                              \
    __builtin_amdgcn_s_setprio(1);                                                  \
    _Pragma("unroll")                                                               \
    for (int i = 0; i < 4; ++i) {                                                   \
      _Pragma("unroll")                                                             \
      for (int n = 0; n < 4; ++n)                                                   \
        acc[i][n] =                                                                 \
            __builtin_amdgcn_mfma_f32_16x16x32_bf16(af[i], bfr[n], acc[i][n], 0, 0, 0); \
    }                                                                               \
    __builtin_amdgcn_s_setprio(0);                                                  \
    __builtin_amdgcn_s_barrier();                                                   \
    /* ---------- phase B: A-frags(m4..7) | stage B halves -------------------- */ \
    _Pragma("unroll")                                                               \
    for (int i = 0; i < 4; ++i)                                                     \
      af[i] = *(const bf16x8*)(Ab_ + aoff + 4096 + i * 1024);                       \
    if (STAGE) {                                                                    \
      gll16(gB + kc_, Bn_ + wv * 512);                                              \
      gll16(gB + (size_t)128 * KDIM + kc_, Bn_ + 4096 + wv * 512);                  \
    }                                                                               \
    __builtin_amdgcn_s_barrier();                                                   \
    asm volatile("s_waitcnt lgkmcnt(0)" ::: "memory");                              \
    __builtin_amdgcn_sched_barrier(0);                                              \
    __builtin_amdgcn_s_setprio(1);                                                  \
    _Pragma("unroll")                                                               \
    for (int i = 0; i < 4; ++i) {                                                   \
      _Pragma("unroll")                                                             \
      for (int n = 0; n < 4; ++n)                                                   \
        acc[4 + i][n] =                                                             \
            __builtin_amdgcn_mfma_f32_16x16x32_bf16(af[i], bfr[n], acc[4 + i][n], 0, 0, 0); \
    }                                                                               \
    __builtin_amdgcn_s_setprio(0);                                                  \
    if (TOKW_) { /* stream tokens: read back own staged A (== Pb bits), scale */   \
      const short* myA_ = Sm + cb_ * 8192 + wv * 512 + lane * 8;                    \
      const bf16x8 v0_ = *(const bf16x8*)myA_;                                      \
      const bf16x8 v1_ = *(const bf16x8*)(myA_ + 4096);                             \
      const size_t c0_ = (size_t)(KT) * 32 + sg;                                    \
      float4 a_, b_;                                                                \
      a_.x = bf16f(v0_[0]) * inv0; a_.y = bf16f(v0_[1]) * inv0;                     \
      a_.z = bf16f(v0_[2]) * inv0; a_.w = bf16f(v0_[3]) * inv0;                     \
      b_.x = bf16f(v0_[4]) * inv0; b_.y = bf16f(v0_[5]) * inv0;                     \
      b_.z = bf16f(v0_[6]) * inv0; b_.w = bf16f(v0_[7]) * inv0;                     \
      *(float4*)&tokens[(size_t)(m0 + srow) * KDIM + c0_] = a_;                     \
      *(float4*)&tokens[(size_t)(m0 + srow) * KDIM + c0_ + 4] = b_;                 \
      a_.x = bf16f(v1_[0]) * inv1; a_.y = bf16f(v1_[1]) * inv1;                     \
      a_.z = bf16f(v1_[2]) * inv1; a_.w = bf16f(v1_[3]) * inv1;                     \
      b_.x = bf16f(v1_[4]) * inv1; b_.y = bf16f(v1_[5]) * inv1;                     \
      b_.z = bf16f(v1_[6]) * inv1; b_.w = bf16f(v1_[7]) * inv1;                     \
      *(float4*)&tokens[(size_t)(m0 + 128 + srow) * KDIM + c0_] = a_;               \
      *(float4*)&tokens[(size_t)(m0 + 128 + srow) * KDIM + c0_ + 4] = b_;           \
    }                                                                               \
    asm volatile("s_waitcnt vmcnt(" #VMN ")" ::: "memory");                         \
    __builtin_amdgcn_s_barrier();                                                   \
    __builtin_amdgcn_sched_barrier(0);                                              \
  }

  if (EPI == 0) {
    for (int kt = 0; kt < NT - 2; ++kt) DO_TILE(kt, 1, 4, 0);
    DO_TILE(NT - 2, 0, 0, 0);
    DO_TILE(NT - 1, 0, 0, 0);
  } else {
    // TOKW run = kt in [16*bx, 16*bx+16); store-aware counted vmcnt per segment
    const int s = bx * 16;
    int kt = 0;
    for (; kt < s; ++kt) DO_TILE(kt, 1, 4, 0);
    DO_TILE(kt, 1, 8, 1);  // first TOKW tile: [ld(kt+1)][ld(kt+2)][st(kt)]
    ++kt;
    for (; kt < s + 16 && kt < NT - 2; ++kt) DO_TILE(kt, 1, 12, 1);
    if (kt == s + 16) {    // first tile after the run: st(kt-1) still in queue
      DO_TILE(kt, 1, 8, 0);
      ++kt;
    }
    for (; kt < NT - 2; ++kt) DO_TILE(kt, 1, 4, 0);
    DO_TILE(NT - 2, 0, 0, ((NT - 2) >> 4) == bx);
    DO_TILE(NT - 1, 0, 0, ((NT - 1) >> 4) == bx);
  }
#undef DO_TILE

  const int gr0 = m0 + wr * 128 + lh * 4;
  const int gc0 = n0 + wc * 64 + lr;
  if (EPI == 0) {
    // direct-U epilogue (compiler schedules the loads)
    float rs[8][4] = {};
#pragma unroll
    for (int m = 0; m < 8; ++m)
#pragma unroll
      for (int n = 0; n < 4; ++n) {
        const int col = gc0 + n * 16;
#pragma unroll
        for (int j = 0; j < 4; ++j) {
          const int row = gr0 + m * 16 + j;
          const size_t idx = (size_t)row * V_DIM + col;
          const float u = U[idx];
          const float e = __expf(acc[m][n][j] - 2.f * __logf(-__logf(u + 1e-10f) + 1e-10f));
          const short eb = f2bf(e);
          Pb[idx] = eb;
          rs[m][j] += bf16f(eb);
        }
      }
#pragma unroll
    for (int m = 0; m < 8; ++m)
#pragma unroll
      for (int j = 0; j < 4; ++j) {
        float s = rs[m][j];
        s += __shfl_xor(s, 1); s += __shfl_xor(s, 2);
        s += __shfl_xor(s, 4); s += __shfl_xor(s, 8);
        if (lr == 0)
          partials[(size_t)(gr0 + m * 16 + j) * 32 + bx * 4 + wc] = s;
      }
  } else {
#pragma unroll
    for (int m = 0; m < 8; ++m)
#pragma unroll
      for (int j = 0; j < 4; ++j) {
        const int row = gr0 + m * 16 + j;
        const float s = invsum[row];
#pragma unroll
        for (int n = 0; n < 4; ++n)
          C[(size_t)row * E_DIM + gc0 + n * 16] = acc[m][n][j] * s;
      }
  }
}

// invsum[r] = 1 / sum(partials[r][0..32))
__global__ __launch_bounds__(256) void k_rowsum_inv(const float* __restrict__ partials,
                                                    float* __restrict__ invsum) {
  const int r = blockIdx.x * 256 + threadIdx.x;
  const float4* p = (const float4*)&partials[(size_t)r * 32];
  float s = 0.f;
#pragma unroll
  for (int i = 0; i < 8; ++i) { float4 v = p[i]; s += v.x + v.y + v.z + v.w; }
  invsum[r] = 1.f / s;
}

// =============== FALLBACK PATH (round-1, known-correct) ======================
__global__ __launch_bounds__(256) void k_gemm_nt(const short* __restrict__ A,
                                                 const short* __restrict__ B,
                                                 float* __restrict__ C,
                                                 int lda, int ldb, int ldc, int K) {
  __shared__ __align__(16) short As[128][64];
  __shared__ __align__(16) short Bs[128][64];
  const int t = threadIdx.x;
  const int w = t >> 6, l = t & 63;
  const int lr = l & 15, lh = l >> 4;
  const int m0 = blockIdx.y * 128, n0 = blockIdx.x * 128;
  const int wm = (w >> 1) * 64, wn = (w & 1) * 64;
  floatx4 acc[4][4] = {};
  for (int k0 = 0; k0 < K; k0 += 64) {
    __syncthreads();
#pragma unroll
    for (int i = 0; i < 4; ++i) {
      const int c = i * 256 + t;
      const int r = c >> 3, c8 = (c & 7) * 8;
      *(bf16x8*)&As[r][c8] = *(const bf16x8*)&A[(size_t)(m0 + r) * lda + k0 + c8];
      *(bf16x8*)&Bs[r][c8] = *(const bf16x8*)&B[(size_t)(n0 + r) * ldb + k0 + c8];
    }
    __syncthreads();
#pragma unroll
    for (int kk = 0; kk < 64; kk += 32) {
      bf16x8 af[4], bfr[4];
#pragma unroll
      for (int m = 0; m < 4; ++m) af[m] = *(const bf16x8*)&As[wm + m * 16 + lr][kk + lh * 8];
#pragma unroll
      for (int n = 0; n < 4; ++n) bfr[n] = *(const bf16x8*)&Bs[wn + n * 16 + lr][kk + lh * 8];
#pragma unroll
      for (int m = 0; m < 4; ++m)
#pragma unroll
        for (int n = 0; n < 4; ++n)
          acc[m][n] = __builtin_amdgcn_mfma_f32_16x16x32_bf16(af[m], bfr[n], acc[m][n], 0, 0, 0);
    }
  }
#pragma unroll
  for (int m = 0; m < 4; ++m)
#pragma unroll
    for (int n = 0; n < 4; ++n) {
      const int col = n0 + wn + n * 16 + lr;
#pragma unroll
      for (int j = 0; j < 4; ++j)
        C[(size_t)(m0 + wm + m * 16 + lh * 4 + j) * ldc + col] = acc[m][n][j];
    }
}

__global__ __launch_bounds__(256) void k_gemm_nt_f32a(const float* __restrict__ A,
                                                      const short* __restrict__ B,
                                                      float* __restrict__ C,
                                                      int lda, int ldb, int ldc, int K) {
  __shared__ __align__(16) short As[128][64];
  __shared__ __align__(16) short Bs[128][64];
  const int t = threadIdx.x;
  const int w = t >> 6, l = t & 63;
  const int lr = l & 15, lh = l >> 4;
  const int m0 = blockIdx.y * 128, n0 = blockIdx.x * 128;
  const int wm = (w >> 1) * 64, wn = (w & 1) * 64;
  floatx4 acc[4][4] = {};
  for (int k0 = 0; k0 < K; k0 += 64) {
    __syncthreads();
#pragma unroll
    for (int i = 0; i < 4; ++i) {
      const int c = i * 256 + t;
      const int r = c >> 3, c8 = (c & 7) * 8;
      const float4 a0 = *(const float4*)&A[(size_t)(m0 + r) * lda + k0 + c8];
      const float4 a1 = *(const float4*)&A[(size_t)(m0 + r) * lda + k0 + c8 + 4];
      bf16x8 va;
      va[0] = f2bf(a0.x); va[1] = f2bf(a0.y); va[2] = f2bf(a0.z); va[3] = f2bf(a0.w);
      va[4] = f2bf(a1.x); va[5] = f2bf(a1.y); va[6] = f2bf(a1.z); va[7] = f2bf(a1.w);
      *(bf16x8*)&As[r][c8] = va;
      *(bf16x8*)&Bs[r][c8] = *(const bf16x8*)&B[(size_t)(n0 + r) * ldb + k0 + c8];
    }
    __syncthreads();
#pragma unroll
    for (int kk = 0; kk < 64; kk += 32) {
      bf16x8 af[4], bfr[4];
#pragma unroll
      for (int m = 0; m < 4; ++m) af[m] = *(const bf16x8*)&As[wm + m * 16 + lr][kk + lh * 8];
#pragma unroll
      for (int n = 0; n < 4; ++n) bfr[n] = *(const bf16x8*)&Bs[wn + n * 16 + lr][kk + lh * 8];
#pragma unroll
      for (int m = 0; m < 4; ++m)
#pragma unroll
        for (int n = 0; n < 4; ++n)
          acc[m][n] = __builtin_amdgcn_mfma_f32_16x16x32_bf16(af[m], bfr[n], acc[m][n], 0, 0, 0);
    }
  }
#pragma unroll
  for (int m = 0; m < 4; ++m)
#pragma unroll
    for (int n = 0; n < 4; ++n) {
      const int col = n0 + wn + n * 16 + lr;
#pragma unroll
      for (int j = 0; j < 4; ++j)
        C[(size_t)(m0 + wm + m * 16 + lh * 4 + j) * ldc + col] = acc[m][n][j];
    }
}

__global__ __launch_bounds__(256) void k_gumbel_softmax(float* __restrict__ S,
                                                        const float* __restrict__ U) {
  const int t = threadIdx.x;
  const int w = t >> 6, l = t & 63;
  const size_t base = (size_t)blockIdx.x * V_DIM + t * 8;
  const float4 s0 = *(const float4*)&S[base];
  const float4 s1 = *(const float4*)&S[base + 4];
  const float4 u0 = *(const float4*)&U[base];
  const float4 u1 = *(const float4*)&U[base + 4];
  float x[8];
  x[0] = s0.x - 2.f * __logf(-__logf(u0.x + 1e-10f) + 1e-10f);
  x[1] = s0.y - 2.f * __logf(-__logf(u0.y + 1e-10f) + 1e-10f);
  x[2] = s0.z - 2.f * __logf(-__logf(u0.z + 1e-10f) + 1e-10f);
  x[3] = s0.w - 2.f * __logf(-__logf(u0.w + 1e-10f) + 1e-10f);
  x[4] = s1.x - 2.f * __logf(-__logf(u1.x + 1e-10f) + 1e-10f);
  x[5] = s1.y - 2.f * __logf(-__logf(u1.y + 1e-10f) + 1e-10f);
  x[6] = s1.z - 2.f * __logf(-__logf(u1.z + 1e-10f) + 1e-10f);
  x[7] = s1.w - 2.f * __logf(-__logf(u1.w + 1e-10f) + 1e-10f);
  float lm = x[0];
#pragma unroll
  for (int i = 1; i < 8; ++i) lm = fmaxf(lm, x[i]);
  lm = wave_max(lm);
  __shared__ float redA[4], redB[4];
  if (l == 0) redA[w] = lm;
  __syncthreads();
  const float m = fmaxf(fmaxf(redA[0], redA[1]), fmaxf(redA[2], redA[3]));
  float p[8];
  float ls = 0.f;
#pragma unroll
  for (int i = 0; i < 8; ++i) { p[i] = __expf(x[i] - m); ls += p[i]; }
  ls = wave_sum(ls);
  if (l == 0) redB[w] = ls;
  __syncthreads();
  const float inv = 1.0f / (redB[0] + redB[1] + redB[2] + redB[3]);
  float4 o0 = make_float4(p[0] * inv, p[1] * inv, p[2] * inv, p[3] * inv);
  float4 o1 = make_float4(p[4] * inv, p[5] * inv, p[6] * inv, p[7] * inv);
  *(float4*)&S[base] = o0;
  *(float4*)&S[base + 4] = o1;
}

extern "C" void kernel_launch(void* const* d_in, const int* in_sizes, int n_in,
                              void* d_out, int out_size, void* d_ws, size_t ws_size,
                              hipStream_t stream) {
  const float* z = (const float*)d_in[0];
  const float* W = (const float*)d_in[1];
  const float* U = (const float*)d_in[2];
  float* tokens = (float*)d_out;                    // [N, V] f32
  float* zq = tokens + (size_t)N_ROWS * V_DIM;      // [N, E] f32
  short* zn = (short*)zq;                           // bf16 zn in z_q region

  short* embn = (short*)d_ws;                       // 4 MB
  short* embnT = embn + (size_t)V_DIM * E_DIM;      // 4 MB

  const size_t NEED = (size_t)V_DIM * E_DIM * 2 * 2     // embn + embnT
                    + (size_t)N_ROWS * 32 * 4           // partials (8 MB)
                    + (size_t)N_ROWS * 4                // invsum
                    + (size_t)N_ROWS * V_DIM * 2;       // P~ bf16 (256 MB)

  k_norm_emb<<<V_DIM, 256, 0, stream>>>(W, embn, embnT);
  k_norm_z<<<N_ROWS / 4, 256, 0, stream>>>(z, zn);

  if (ws_size >= NEED) {
    float* partials = (float*)(embnT + (size_t)V_DIM * E_DIM);
    float* invsum = partials + (size_t)N_ROWS * 32;
    short* Pb = (short*)(invsum + N_ROWS);
    // GEMM1 fused gumbel-exp: grid = (65536/256) * (2048/256) = 2048
    k_gemm8<E_DIM, 8, 0><<<2048, 512, 0, stream>>>(
        zn, embn, U, Pb, partials, nullptr, nullptr, nullptr, 2048 / 8);
    k_rowsum_inv<<<N_ROWS / 256, 256, 0, stream>>>(partials, invsum);
    // GEMM2 scaled + streamed tokens: grid = (65536/256) * (1024/256) = 1024
    k_gemm8<V_DIM, 4, 1><<<1024, 512, 0, stream>>>(
        Pb, embnT, nullptr, nullptr, nullptr, invsum, zq, tokens, 1024 / 8);
  } else {
    k_gemm_nt<<<dim3(V_DIM / 128, N_ROWS / 128), 256, 0, stream>>>(
        zn, embn, tokens, E_DIM, E_DIM, V_DIM, E_DIM);
    k_gumbel_softmax<<<N_ROWS, 256, 0, stream>>>(tokens, U);
    k_gemm_nt_f32a<<<dim3(E_DIM / 128, N_ROWS / 128), 256, 0, stream>>>(
        tokens, embnT, zq, V_DIM, V_DIM, E_DIM, V_DIM);
  }
}